// Round 15
// baseline (857.171 us; speedup 1.0000x reference)
//
#include <hip/hip_runtime.h>
#include <hip/hip_bf16.h>
#include <math.h>

// R15: k_corr -> two-pass channel-split staging (LDS 75KB -> 38KB: 4 blocks/CU),
// q prefetched before staging, kinv accumulated across passes.
// k_project fused into k_conv_half (SRF dot on in-register acc).

#define HH 256
#define WWI 256
#define HW 65536
#define CH 31
#define CIN2 62
#define CM 3
#define CE 128
#define REGC 288
#define C1S 1e-4f
#define C2S 9e-4f

typedef unsigned short u16;
typedef unsigned int u32;
typedef short bf16x8 __attribute__((ext_vector_type(8)));
typedef float f32x4 __attribute__((ext_vector_type(4)));

__device__ __forceinline__ float blo(u32 u){ return __uint_as_float(u << 16); }
__device__ __forceinline__ float bhi(u32 u){ return __uint_as_float(u & 0xffff0000u); }
__device__ __forceinline__ float b1f(u16 u){ return __uint_as_float(((u32)u) << 16); }
__device__ __forceinline__ u16 f2b(float f){
    u32 u = __float_as_uint(f);
    u32 r = (u + 0x7fffu + ((u >> 16) & 1u)) >> 16;
    return (u16)r;
}
__device__ __forceinline__ f32x4 mfma16(bf16x8 a, bf16x8 b, f32x4 c){
    return __builtin_amdgcn_mfma_f32_16x16x32_bf16(a, b, c, 0, 0, 0);
}

// ---------------- 1) conv_half + project fused --------------------------------------
__global__ void k_conv_half(const float* __restrict__ x, const float* __restrict__ w,
                            const float* __restrict__ bias, const float* __restrict__ srf,
                            u16* __restrict__ x31, float* __restrict__ xp){
    __shared__ float sw[CH*CIN2];
    __shared__ float sb[CH+1];
    __shared__ float ssrf[CM*CH];
    for(int i=threadIdx.x;i<CH*CIN2;i+=256) sw[i]=w[i];
    for(int i=threadIdx.x;i<CH;i+=256) sb[i]=bias[i];
    for(int i=threadIdx.x;i<CM*CH;i+=256) ssrf[i]=srf[i];
    __syncthreads();
    int pixg = blockIdx.x*256 + threadIdx.x;
    int b = pixg>>16, hw = pixg&65535;
    float acc[CH];
    #pragma unroll
    for(int c=0;c<CH;c++) acc[c]=sb[c];
    for(int ci=0;ci<CIN2;ci++){
        float xv = x[((size_t)(b*CIN2+ci))*HW + hw];
        #pragma unroll
        for(int c=0;c<CH;c++) acc[c] += sw[c*CIN2+ci]*xv;
    }
    u16* o = x31 + (size_t)pixg*32;
    #pragma unroll
    for(int c=0;c<CH;c++) o[c]=f2b(acc[c]);
    o[31]=0;
    // fused project: xp = clip(SRF @ acc, -1, 1)
    #pragma unroll
    for(int m=0;m<CM;m++){
        float a=0.f;
        #pragma unroll
        for(int c=0;c<CH;c++) a += ssrf[m*CH+c]*acc[c];
        a = fminf(fmaxf(a,-1.f),1.f);
        xp[((size_t)(b*CM+m))*HW + hw] = a;
    }
}

// ---------------- 3a) stats stage 1 ---------------------------------------------------
__global__ void k_stats1(const float* __restrict__ xp, const float* __restrict__ y,
                         float2* __restrict__ part, int NB){
    int bid = blockIdx.x;
    int p = bid >> 6, c = bid & 63;
    const float* src = (p<3*NB) ? (xp + (size_t)p*HW) : (y + (size_t)(p-3*NB)*HW);
    const float4* s4 = (const float4*)(src + c*1024);
    float4 v = s4[threadIdx.x];
    float s  = v.x + v.y + v.z + v.w;
    float ss = v.x*v.x + v.y*v.y + v.z*v.z + v.w*v.w;
    #pragma unroll
    for(int t=1;t<64;t<<=1){ s += __shfl_xor(s,t); ss += __shfl_xor(ss,t); }
    __shared__ float rs[4], rss[4];
    int wid = threadIdx.x>>6, lane = threadIdx.x&63;
    if(lane==0){ rs[wid]=s; rss[wid]=ss; }
    __syncthreads();
    if(threadIdx.x==0){
        part[bid] = float2{rs[0]+rs[1]+rs[2]+rs[3], rss[0]+rss[1]+rss[2]+rss[3]};
    }
}

// ---------------- 3b) stats stage 2 ---------------------------------------------------
__global__ void k_stats2(const float2* __restrict__ part, float* __restrict__ stats){
    int p = blockIdx.x;
    float2 pa = part[p*64 + threadIdx.x];
    float s = pa.x, ss = pa.y;
    #pragma unroll
    for(int t=1;t<64;t<<=1){ s += __shfl_xor(s,t); ss += __shfl_xor(ss,t); }
    if(threadIdx.x==0){
        float mean = s/(float)HW;
        float var = (ss - s*s/(float)HW) / (float)(HW-1);
        stats[p*2]   = mean;
        stats[p*2+1] = sqrtf(fmaxf(var,0.f));
    }
}

// ---------------- 4) fused SSIM (align + 2D gaussian + difficulty) --------------------
__global__ __launch_bounds__(256) void k_ssim(const float* __restrict__ xp,
                                              const float* __restrict__ y,
                                              const float* __restrict__ stats,
                                              float* __restrict__ diff,
                                              u16* __restrict__ regin, int NB){
    __shared__ float sxa[1600];
    __shared__ float sy2[1600];
    __shared__ float hs[5][1280];
    int t = threadIdx.x;
    int bid = blockIdx.x;
    int bb = bid >> 6;
    int s2 = bid & 63;
    int tx = s2 & 7, ty = s2 >> 3;
    float g[9]; float gs = 0.f;
    #pragma unroll
    for(int k=0;k<9;k++){ float cc=(float)(k-4); g[k]=expf(-cc*cc/4.5f); gs+=g[k]; }
    float ginv = 1.f/gs;
    #pragma unroll
    for(int k=0;k<9;k++) g[k] *= ginv;

    float msum[4] = {0.f,0.f,0.f,0.f};
    for(int m=0;m<3;m++){
        int plane = bb*3+m;
        float sm = stats[plane*2],        ssd = stats[plane*2+1];
        float rm = stats[(plane+3*NB)*2], rsd = stats[(plane+3*NB)*2+1];
        const float* xpp = xp + (size_t)plane*HW;
        const float* yp  = y  + (size_t)plane*HW;
        if(m) __syncthreads();
        #pragma unroll
        for(int it=0; it<7; ++it){
            int s = it*256 + t;
            if(s < 1600){
                int rr = s/40, cc = s - rr*40;
                int gy = ty*32-4+rr, gx = tx*32-4+cc;
                float xv=0.f, yv=0.f;
                if(((unsigned)gy<256u)&&((unsigned)gx<256u)){
                    float v = xpp[(gy<<8)+gx];
                    v = (v-sm)/(ssd+1e-6f)*rsd + rm;
                    xv = fminf(fmaxf(v,-1.f),1.f);
                    yv = yp[(gy<<8)+gx];
                }
                sxa[s]=xv; sy2[s]=yv;
            }
        }
        __syncthreads();
        #pragma unroll
        for(int it=0; it<5; ++it){
            int s = it*256 + t;
            int rr = s>>5, cc = s&31;
            int base = rr*40 + cc;
            float s0=0,s1=0,s2v=0,s3=0,s4=0;
            #pragma unroll
            for(int k=0;k<9;k++){
                float gg=g[k];
                float a=sxa[base+k], b=sy2[base+k];
                s0+=gg*a; s1+=gg*b; s2v+=gg*a*a; s3+=gg*b*b; s4+=gg*a*b;
            }
            hs[0][s]=s0; hs[1][s]=s1; hs[2][s]=s2v; hs[3][s]=s3; hs[4][s]=s4;
        }
        __syncthreads();
        #pragma unroll
        for(int it=0; it<4; ++it){
            int s = it*256 + t;
            int rr = s>>5, cc = s&31;
            float v0=0,v1=0,v2=0,v3=0,v4=0;
            #pragma unroll
            for(int k=0;k<9;k++){
                float gg=g[k];
                int idx=(rr+k)*32+cc;
                v0+=gg*hs[0][idx]; v1+=gg*hs[1][idx]; v2+=gg*hs[2][idx];
                v3+=gg*hs[3][idx]; v4+=gg*hs[4][idx];
            }
            float mu1=v0, mu2=v1;
            float mu1s=mu1*mu1, mu2s=mu2*mu2, mu12=mu1*mu2;
            float sg1=v2-mu1s, sg2=v3-mu2s, sg12=v4-mu12;
            msum[it] += (2.f*mu12+C1S)*(2.f*sg12+C2S)
                      / ((mu1s+mu2s+C1S)*(sg1+sg2+C2S));
        }
    }
    #pragma unroll
    for(int it=0; it<4; ++it){
        int s = it*256 + t;
        int rr = s>>5, cc = s&31;
        int pixg = (bb<<16) + ((ty*32+rr)<<8) + (tx*32+cc);
        float d = fminf(fmaxf((1.f-msum[it]*(1.f/3.f))*0.5f,0.f),1.f);
        diff[pixg] = d;
        regin[(size_t)pixg*REGC + 281] = f2b(d);
    }
}

// ---------------- 7) q,k 1x1 convs -> regin bf16 (32 px per block) --------------------
__global__ __launch_bounds__(128) void k_qk(const u16* __restrict__ x31,
                     const float* __restrict__ y,
                     const float* __restrict__ qw, const float* __restrict__ qb,
                     const float* __restrict__ kw, const float* __restrict__ kb,
                     u16* __restrict__ regin){
    __shared__ float sqw[CE*CH];
    __shared__ float skw[CE*CM];
    __shared__ float sqb[CE], skb[CE];
    for(int i=threadIdx.x;i<CE*CH;i+=128) sqw[i]=qw[i];
    for(int i=threadIdx.x;i<CE*CM;i+=128) skw[i]=kw[i];
    if(threadIdx.x<CE){ sqb[threadIdx.x]=qb[threadIdx.x]; skb[threadIdx.x]=kb[threadIdx.x]; }
    __syncthreads();
    int co = threadIdx.x;
    int p0 = blockIdx.x*32;
    float wk0 = skw[co*CM+0], wk1 = skw[co*CM+1], wk2 = skw[co*CM+2];
    for(int pp=0;pp<32;pp++){
        int pixg = p0+pp;
        int b = pixg>>16, hw = pixg&65535;
        const u16* xr = x31 + (size_t)pixg*32;
        float acc = sqb[co];
        #pragma unroll
        for(int c=0;c<CH;c++) acc += sqw[co*CH+c]*b1f(xr[c]);
        u16* rg = regin + (size_t)pixg*REGC;
        rg[co] = f2b(acc);
        float ack = skb[co] + wk0*y[((size_t)(b*CM  ))*HW+hw]
                            + wk1*y[((size_t)(b*CM+1))*HW+hw]
                            + wk2*y[((size_t)(b*CM+2))*HW+hw];
        rg[128+co] = f2b(ack);
        if(co<6) rg[282+co] = 0;
    }
}

// ---------------- 9) correlation volume: two-pass channel-split LDS staging -----------
// Block: 32x4 px tile, 256 thr. Per pass: 64 K-channels staged (36.9KB) -> 4 blocks/CU.
// q prefetched before staging; dots + kinv sums accumulate across passes.
__global__ __launch_bounds__(256, 4) void k_corr(const u16* __restrict__ regin,
                                                 u16* __restrict__ regout){
    __shared__ uint4 klv[288*8];       // 36,864 B
    __shared__ float kinvl[288];       // 1,152 B
    int t = threadIdx.x;
    int half = t & 1, pidx = t >> 1;           // 128 px per block
    int bid = blockIdx.x;
    int bb = bid >> 9;                          // batch
    int s2 = bid & 511;
    int tx = s2 & 7, ty = s2 >> 3;              // 8 x 64 tiles of 32x4
    int lw = pidx & 31, lh = pidx >> 5;
    int w = tx*32 + lw;
    int h = ty*4 + lh;
    int pixg = (bb<<16) + (h<<8) + w;

    // q prefetch (this lane's 8 uint4 = ch {half*64..} split across the 2 passes)
    const uint4* qbase = (const uint4*)(regin + (size_t)pixg*REGC);
    uint4 q0[4], q1[4];
    #pragma unroll
    for(int i=0;i<4;i++){ q0[i] = qbase[half*4 + i]; q1[i] = qbase[8 + half*4 + i]; }
    float sq = 0.f;
    #pragma unroll
    for(int i=0;i<4;i++){
        uint4 a = q0[i], b = q1[i];
        sq += blo(a.x)*blo(a.x)+bhi(a.x)*bhi(a.x) + blo(a.y)*blo(a.y)+bhi(a.y)*bhi(a.y)
            + blo(a.z)*blo(a.z)+bhi(a.z)*bhi(a.z) + blo(a.w)*blo(a.w)+bhi(a.w)*bhi(a.w);
        sq += blo(b.x)*blo(b.x)+bhi(b.x)*bhi(b.x) + blo(b.y)*blo(b.y)+bhi(b.y)*bhi(b.y)
            + blo(b.z)*blo(b.z)+bhi(b.z)*bhi(b.z) + blo(b.w)*blo(b.w)+bhi(b.w)*bhi(b.w);
    }
    sq += __shfl_xor(sq, 1);
    float qn = 1.f/fmaxf(sqrtf(sq),1e-12f);

    float res[13];
    #pragma unroll
    for(int i=0;i<13;i++) res[i]=0.f;
    float ksum[3] = {0.f,0.f,0.f};

    #pragma unroll
    for(int pass=0; pass<2; ++pass){
        if(pass) __syncthreads();               // protect klv reuse
        // stage 288 halo px x 8 uint4 (channels pass*64 .. +63), edge clamp baked in
        #pragma unroll
        for(int it=0; it<9; ++it){              // 2304 slots
            int s = it*256 + t;
            int rpx = s >> 3, g = s & 7;
            int rr = rpx/36, cc = rpx - rr*36;
            int gy = min(max(ty*4-2+rr,0),255);
            int gx = min(max(tx*32-2+cc,0),255);
            const uint4* src = (const uint4*)(regin + ((size_t)((bb<<16)+(gy<<8)+gx))*REGC + 128)
                             + pass*8;
            klv[rpx*8 + (g ^ (rpx&7))] = src[g];
        }
        __syncthreads();
        // kinv partial sums: 576 (px,half) items
        #pragma unroll
        for(int it=0; it<3; ++it){
            int item = it*256 + t;
            if(item < 576){
                int px = item>>1, hf = item&1;
                const uint4* kp = &klv[px*8];
                int sw = px & 7;
                float s = 0.f;
                #pragma unroll
                for(int i=0;i<4;i++){
                    uint4 kv = kp[(hf*4+i)^sw];
                    s += blo(kv.x)*blo(kv.x)+bhi(kv.x)*bhi(kv.x)
                       + blo(kv.y)*blo(kv.y)+bhi(kv.y)*bhi(kv.y)
                       + blo(kv.z)*blo(kv.z)+bhi(kv.z)*bhi(kv.z)
                       + blo(kv.w)*blo(kv.w)+bhi(kv.w)*bhi(kv.w);
                }
                ksum[it] += s;
            }
        }
        // partial dots for 25 offsets
        #pragma unroll
        for(int dy=-2;dy<=2;dy++){
            #pragma unroll
            for(int dx=-2;dx<=2;dx++){
                int rpx = (lh+2+dy)*36 + (lw+2+dx);
                const uint4* kp = &klv[rpx*8];
                int sw = rpx & 7;
                float s = 0.f;
                #pragma unroll
                for(int i=0;i<4;i++){
                    uint4 kv = kp[(half*4 + i) ^ sw];
                    uint4 qv = pass ? q1[i] : q0[i];
                    s += blo(qv.x)*blo(kv.x) + bhi(qv.x)*bhi(kv.x);
                    s += blo(qv.y)*blo(kv.y) + bhi(qv.y)*bhi(kv.y);
                    s += blo(qv.z)*blo(kv.z) + bhi(qv.z)*bhi(kv.z);
                    s += blo(qv.w)*blo(kv.w) + bhi(qv.w)*bhi(kv.w);
                }
                s += __shfl_xor(s, 1);
                int o = (dy+2)*5 + (dx+2);
                if(o < 13){ if(half==0) res[o] += s; }
                else      { if(half==1) res[o-13] += s; }
            }
        }
    }

    // finalize kinv (pair-shfl combine), then scale + packed stores
    #pragma unroll
    for(int it=0; it<3; ++it){
        int item = it*256 + t;
        float so = ksum[it] + __shfl_xor(ksum[it],1);
        if(item < 576 && (item&1)==0) kinvl[item>>1] = 1.f/fmaxf(sqrtf(so),1e-12f);
    }
    __syncthreads();

    u16* rg = regout + (size_t)pixg*REGC + 256;
    if(half==0){
        u16 p[13];
        #pragma unroll
        for(int i=0;i<13;i++){
            int rpx = (lh+2+(i/5-2))*36 + (lw+2+(i%5-2));
            p[i] = f2b(res[i]*qn*kinvl[rpx]);
        }
        uint4 v0; u32* v0p = (u32*)&v0;
        #pragma unroll
        for(int i=0;i<4;i++) v0p[i] = (u32)p[2*i] | ((u32)p[2*i+1]<<16);
        *(uint4*)(rg) = v0;
        *(u32*)(rg+8)  = (u32)p[8]  | ((u32)p[9]<<16);
        *(u32*)(rg+10) = (u32)p[10] | ((u32)p[11]<<16);
        rg[12] = p[12];
    } else {
        u16 p[12];
        #pragma unroll
        for(int i=0;i<12;i++){
            int o = 13+i;
            int rpx = (lh+2+(o/5-2))*36 + (lw+2+(o%5-2));
            p[i] = f2b(res[i]*qn*kinvl[rpx]);
        }
        rg[13] = p[0];
        *(u32*)(rg+14) = (u32)p[1] | ((u32)p[2]<<16);
        uint4 v1; u32* v1p = (u32*)&v1;
        #pragma unroll
        for(int i=0;i<4;i++) v1p[i] = (u32)p[3+2*i] | ((u32)p[4+2*i]<<16);
        *(uint4*)(rg+16) = v1;
        rg[24] = p[11];
    }
}

// ---------------- 10) weight rearrange + zpad clear -----------------------------------
__global__ void k_wre(const float* __restrict__ w1, const float* __restrict__ w2,
                      u16* __restrict__ w1f, u16* __restrict__ w2f,
                      u16* __restrict__ zpad){
    int i = blockIdx.x*256 + threadIdx.x;
    if(i < 32) zpad[i] = 0;
    if(i < 9*9*128*32){
        int j = i & 7;
        int gg = (i>>3)&3;
        int co = (i>>5)&127;
        int rest = i>>12;
        int kbg = rest%9, tap = rest/9;
        int ci = kbg*32 + gg*8 + j;
        float v = (ci<282) ? w1[((size_t)co*282 + ci)*9 + tap] : 0.f;
        w1f[i] = f2b(v);
    }
    if(i < 9*4*64*32){
        int j = i & 7;
        int gg = (i>>3)&3;
        int co = (i>>5)&63;
        int rest = i>>11;
        int kbg = rest&3, tap = rest>>2;
        int ci = kbg*32 + gg*8 + j;
        w2f[i] = f2b(w2[((size_t)co*128 + ci)*9 + tap]);
    }
}

// ---------------- 11+12) MFMA 3x3 conv (implicit GEMM over taps) ----------------------
template<int MF>
__device__ __forceinline__ void ldaM(const uint4* sbuf, int ky, int kx, int kb,
                                     int lane15, int lgrp, bf16x8* ar){
    #pragma unroll
    for(int mf=0;mf<MF;mf++){
        int spx  = (mf&1)*16 + lane15 + kx;
        int srow = (mf>>1) + ky;
        int slot = (srow*34 + spx)*8 + ((kb*4 + lgrp) ^ (spx&7));
        ar[mf] = *(const bf16x8*)&sbuf[slot];
    }
}

template<int NF, int KBGT, int NCO>
__device__ __forceinline__ void ldbN(const u16* __restrict__ wf, int kbg, int tap,
                                     int co0, int lane15, int lgrp, bf16x8* br){
    #pragma unroll
    for(int nf=0;nf<NF;nf++){
        size_t idx = ((size_t)((tap*KBGT + kbg)*NCO + co0 + nf*16 + lane15))*4 + lgrp;
        br[nf] = *(const bf16x8*)(wf + idx*8);
    }
}

template<int MF, int NF, int KBGT, int NCO, int KBI>
__device__ __forceinline__ void conv_steps(const uint4* sbuf, const u16* __restrict__ wf,
                                           int kbgbase, int co0, int lane15, int lgrp,
                                           f32x4 (&acc)[MF][NF]){
    constexpr int NST = 9*KBI;
    #pragma unroll
    for(int s=0;s<NST;s++){
        int ky,kx,kb;
        if(KBI==2){ ky = s/6; kx = (s>>1)%3; kb = s&1; }
        else      { ky = s/3; kx = s%3;      kb = 0;   }
        bf16x8 a[MF];
        bf16x8 b[NF];
        ldaM<MF>(sbuf, ky,kx,kb, lane15, lgrp, a);
        ldbN<NF,KBGT,NCO>(wf, kbgbase+kb, ky*3+kx, co0, lane15, lgrp, b);
        #pragma unroll
        for(int mf=0;mf<MF;mf++)
            #pragma unroll
            for(int nf=0;nf<NF;nf++)
                acc[mf][nf] = mfma16(a[mf], b[nf], acc[mf][nf]);
    }
}

template<int CSTRIDE, int CINTOT, int NCO, int KBGT, int TM>
__global__ __launch_bounds__(128, 1) void k_conv3(const u16* __restrict__ in,
                                                  const u16* __restrict__ wf,
                                                  const float* __restrict__ bias,
                                                  u16* __restrict__ out,
                                                  const u16* __restrict__ zpad){
    constexpr int NW = 2;
    constexpr int NF = NCO/(16*NW);
    constexpr int MF = 2*TM;
    constexpr int NCHUNK = (CINTOT + 63)/64;
    constexpr int NTH = NW*64;
    constexpr int SLOTS = (TM+2)*34*8;
    __shared__ uint4 sT[2*SLOTS];
    int t = threadIdx.x;
    int lane15 = t & 15, lgrp = (t >> 4) & 3;
    int co0 = (t >> 6) * (NCO/NW);
    int rb = blockIdx.x;
    int bid = (rb & 7)*(gridDim.x >> 3) + (rb >> 3);
    int bb = bid >> 9;
    int s2 = bid & 511;
    int tx = s2 & 7, ty = s2 >> 3;
    int row0 = ty*TM, col0 = tx*32;
    const u16* inb  = in  + (size_t)bb*HW*CSTRIDE;
    u16*       outb = out + (size_t)bb*HW*NCO;

    f32x4 acc[MF][NF];
    #pragma unroll
    for(int nf=0;nf<NF;nf++){
        float bsv = bias[co0 + nf*16 + lane15];
        #pragma unroll
        for(int mf=0;mf<MF;mf++) acc[mf][nf] = f32x4{bsv,bsv,bsv,bsv};
    }

    auto stage = [&](int buf, int kc){
        constexpr int NIT = (SLOTS + NTH - 1)/NTH;
        #pragma unroll
        for(int it=0; it<NIT; ++it){
            int s = it*NTH + t;
            if(s >= SLOTS) continue;
            int srow = s/272, rem = s - srow*272;
            int spx = rem>>3, ggp = rem&7;
            int gg = ggp ^ (spx&7);
            int gy = row0-1+srow, gx = col0-1+spx;
            bool ok = ((unsigned)gy<256u) && ((unsigned)gx<256u);
            const u16* src = ok ? (inb + (size_t)((gy<<8)+gx)*CSTRIDE + kc + gg*8) : zpad;
            __builtin_amdgcn_global_load_lds(
                (const __attribute__((address_space(1))) u32*)src,
                (__attribute__((address_space(3))) u32*)&sT[buf*SLOTS + s],
                16, 0, 0);
        }
    };

    stage(0, 0);
    __syncthreads();

    int cur = 0;
    for(int j=0;j<NCHUNK;j++){
        if(j+1 < NCHUNK) stage(cur^1, (j+1)*64);
        if(CINTOT==288 && j==NCHUNK-1)
            conv_steps<MF,NF,KBGT,NCO,1>(&sT[cur*SLOTS], wf, j*2, co0, lane15, lgrp, acc);
        else
            conv_steps<MF,NF,KBGT,NCO,2>(&sT[cur*SLOTS], wf, j*2, co0, lane15, lgrp, acc);
        if(j+1 < NCHUNK){
            __syncthreads();
            cur ^= 1;
        }
    }

    #pragma unroll
    for(int mf=0;mf<MF;mf++){
        int prow  = row0 + (mf>>1);
        int pcolb = col0 + (mf&1)*16 + lgrp*4;
        #pragma unroll
        for(int nf=0;nf<NF;nf++){
            int co = co0 + nf*16 + lane15;
            #pragma unroll
            for(int r=0;r<4;r++){
                int pix = (prow<<8) + pcolb + r;
                float v = acc[mf][nf][r];
                v = (v>0.f) ? v : 0.2f*v;
                outb[(size_t)pix*NCO + co] = f2b(v);
            }
        }
    }
}

// ---------------- 13) flow (1x1 conv + tanh) + bilinear warp --------------------------
__device__ __forceinline__ float reflectc(float coord, float size){
    float c = fabsf(coord + 0.5f);
    float extra = fmodf(c, size);
    float flips = floorf(c/size);
    float fo = fmodf(flips, 2.0f);
    float r = (fo == 0.0f) ? (extra - 0.5f) : (size - extra - 0.5f);
    return fminf(fmaxf(r, 0.0f), size - 1.0f);
}

__global__ void k_flowwarp(const u16* __restrict__ h2, const float* __restrict__ w3,
                           const float* __restrict__ b3, const float* __restrict__ diff,
                           const u16* __restrict__ x31, float* __restrict__ out){
    __shared__ float sw[130];
    for(int i=threadIdx.x;i<128;i+=256) sw[i]=w3[i];
    if(threadIdx.x<2) sw[128+threadIdx.x]=b3[threadIdx.x];
    __syncthreads();
    int pixg = blockIdx.x*256 + threadIdx.x;
    int b = pixg>>16, hw = pixg&65535, h = hw>>8, w = hw&255;
    const uint4* h4 = (const uint4*)(h2 + (size_t)pixg*64);
    float f0 = sw[128], f1 = sw[129];
    #pragma unroll
    for(int cc=0;cc<8;cc++){
        uint4 u = h4[cc];
        float vv[8] = {blo(u.x),bhi(u.x),blo(u.y),bhi(u.y),blo(u.z),bhi(u.z),blo(u.w),bhi(u.w)};
        #pragma unroll
        for(int j=0;j<8;j++){ int c = cc*8+j; f0 += sw[c]*vv[j]; f1 += sw[64+c]*vv[j]; }
    }
    float d = diff[pixg];
    f0 = tanhf(f0)*2.0f*d;
    f1 = tanhf(f1)*2.0f*d;
    float ix = reflectc((float)w + f0, 256.f);
    float iy = reflectc((float)h + f1, 256.f);
    float x0 = floorf(ix), y0 = floorf(iy);
    float wx = ix-x0, wy = iy-y0;
    int x0i = min(max((int)x0,0),255);
    int x1i = min(x0i+1,255);
    int y0i = min(max((int)y0,0),255);
    int y1i = min(y0i+1,255);
    const u16* p00 = x31 + ((size_t)((b<<16)+(y0i<<8)+x0i))*32;
    const u16* p01 = x31 + ((size_t)((b<<16)+(y0i<<8)+x1i))*32;
    const u16* p10 = x31 + ((size_t)((b<<16)+(y1i<<8)+x0i))*32;
    const u16* p11 = x31 + ((size_t)((b<<16)+(y1i<<8)+x1i))*32;
    float w00=(1.f-wy)*(1.f-wx), w01=(1.f-wy)*wx, w10=wy*(1.f-wx), w11=wy*wx;
    float* ob = out + (size_t)b*CH*HW + hw;
    #pragma unroll
    for(int c=0;c<CH;c++){
        ob[(size_t)c*HW] = w00*b1f(p00[c]) + w01*b1f(p01[c])
                         + w10*b1f(p10[c]) + w11*b1f(p11[c]);
    }
}

extern "C" void kernel_launch(void* const* d_in, const int* in_sizes, int n_in,
                              void* d_out, int out_size, void* d_ws, size_t ws_size,
                              hipStream_t stream) {
    const float* x    = (const float*)d_in[0];
    const float* y    = (const float*)d_in[1];
    const float* srf  = (const float*)d_in[2];
    const float* chw  = (const float*)d_in[3];
    const float* chb  = (const float*)d_in[4];
    const float* qw   = (const float*)d_in[5];
    const float* qb   = (const float*)d_in[6];
    const float* kw   = (const float*)d_in[7];
    const float* kb   = (const float*)d_in[8];
    const float* w1   = (const float*)d_in[9];
    const float* b1p  = (const float*)d_in[10];
    const float* w2   = (const float*)d_in[11];
    const float* b2p  = (const float*)d_in[12];
    const float* w3   = (const float*)d_in[13];
    const float* b3p  = (const float*)d_in[14];

    struct Arena {
        u16 *x31, *regin, *h1, *h2, *w1f, *w2f, *zpad;
        float *xp, *stats, *diff;
        float2 *part;
    };
    auto layout = [&](char* base, int G, Arena* A)->size_t{
        size_t o = 0;
        auto take = [&](size_t sz)->char*{ char* p = base ? base+o : 0; o += (sz+255)&~255ull; return p; };
        Arena tmpA; Arena* P = A ? A : &tmpA;
        P->x31   = (u16*)  take((size_t)G*HW*32*2);
        P->xp    = (float*)take((size_t)G*3*HW*4);
        P->stats = (float*)take(6*4*2*4);
        P->part  = (float2*)take((size_t)6*4*64*8);
        P->diff  = (float*)take((size_t)G*HW*4);
        P->regin = (u16*)  take((size_t)G*HW*REGC*2);
        P->h1    = (u16*)  take((size_t)G*HW*128*2);
        P->h2    = (u16*)  take((size_t)G*HW*64*2);
        P->w1f   = (u16*)  take((size_t)9*9*128*32*2);
        P->w2f   = (u16*)  take((size_t)9*4*64*32*2);
        P->zpad  = (u16*)  take(64);
        return o;
    };

    int G = 4;
    while(G > 1 && layout(nullptr, G, nullptr) > ws_size) G >>= 1;
    Arena A;
    layout((char*)d_ws, G, &A);

    k_wre<<<1296, 256, 0, stream>>>(w1, w2, A.w1f, A.w2f, A.zpad);

    for(int g0=0; g0<4; g0+=G){
        int NB = G;
        const float* xg  = x + (size_t)g0*CIN2*HW;
        const float* yg  = y + (size_t)g0*CM*HW;
        float* outg      = (float*)d_out + (size_t)g0*CH*HW;

        k_conv_half<<<NB*256,  256, 0, stream>>>(xg, chw, chb, srf, A.x31, A.xp);
        k_stats1   <<<NB*384,  256, 0, stream>>>(A.xp, yg, A.part, NB);
        k_stats2   <<<NB*6,     64, 0, stream>>>(A.part, A.stats);
        k_ssim     <<<NB*64,   256, 0, stream>>>(A.xp, yg, A.stats, A.diff, A.regin, NB);
        k_qk       <<<NB*2048, 128, 0, stream>>>(A.x31, yg, qw, qb, kw, kb, A.regin);
        k_corr     <<<NB*512,  256, 0, stream>>>(A.regin, A.regin);
        k_conv3<288,288,128,9,4><<<NB*512, 128, 0, stream>>>(A.regin, A.w1f, b1p, A.h1, A.zpad);
        k_conv3<128,128, 64,4,4><<<NB*512, 128, 0, stream>>>(A.h1, A.w2f, b2p, A.h2, A.zpad);
        k_flowwarp <<<NB*256,  256, 0, stream>>>(A.h2, w3, b3p, A.diff, A.x31, outg);
    }
}

// Round 16
// 714.760 us; speedup vs baseline: 1.1992x; 1.1992x over previous
//
#include <hip/hip_runtime.h>
#include <hip/hip_bf16.h>
#include <math.h>

// R16: revert k_corr to R14's proven single-pass 32x4 kernel (R15's two-pass
// channel-split added 3 extra barriers + serialized staging -> +137us regression).
// Keep R15's conv_half+project fusion (saves 67MB re-read + one dispatch).

#define HH 256
#define WWI 256
#define HW 65536
#define CH 31
#define CIN2 62
#define CM 3
#define CE 128
#define REGC 288
#define C1S 1e-4f
#define C2S 9e-4f

typedef unsigned short u16;
typedef unsigned int u32;
typedef short bf16x8 __attribute__((ext_vector_type(8)));
typedef float f32x4 __attribute__((ext_vector_type(4)));

__device__ __forceinline__ float blo(u32 u){ return __uint_as_float(u << 16); }
__device__ __forceinline__ float bhi(u32 u){ return __uint_as_float(u & 0xffff0000u); }
__device__ __forceinline__ float b1f(u16 u){ return __uint_as_float(((u32)u) << 16); }
__device__ __forceinline__ u16 f2b(float f){
    u32 u = __float_as_uint(f);
    u32 r = (u + 0x7fffu + ((u >> 16) & 1u)) >> 16;
    return (u16)r;
}
__device__ __forceinline__ f32x4 mfma16(bf16x8 a, bf16x8 b, f32x4 c){
    return __builtin_amdgcn_mfma_f32_16x16x32_bf16(a, b, c, 0, 0, 0);
}

// ---------------- 1) conv_half + project fused --------------------------------------
__global__ void k_conv_half(const float* __restrict__ x, const float* __restrict__ w,
                            const float* __restrict__ bias, const float* __restrict__ srf,
                            u16* __restrict__ x31, float* __restrict__ xp){
    __shared__ float sw[CH*CIN2];
    __shared__ float sb[CH+1];
    __shared__ float ssrf[CM*CH];
    for(int i=threadIdx.x;i<CH*CIN2;i+=256) sw[i]=w[i];
    for(int i=threadIdx.x;i<CH;i+=256) sb[i]=bias[i];
    for(int i=threadIdx.x;i<CM*CH;i+=256) ssrf[i]=srf[i];
    __syncthreads();
    int pixg = blockIdx.x*256 + threadIdx.x;
    int b = pixg>>16, hw = pixg&65535;
    float acc[CH];
    #pragma unroll
    for(int c=0;c<CH;c++) acc[c]=sb[c];
    for(int ci=0;ci<CIN2;ci++){
        float xv = x[((size_t)(b*CIN2+ci))*HW + hw];
        #pragma unroll
        for(int c=0;c<CH;c++) acc[c] += sw[c*CIN2+ci]*xv;
    }
    u16* o = x31 + (size_t)pixg*32;
    #pragma unroll
    for(int c=0;c<CH;c++) o[c]=f2b(acc[c]);
    o[31]=0;
    #pragma unroll
    for(int m=0;m<CM;m++){
        float a=0.f;
        #pragma unroll
        for(int c=0;c<CH;c++) a += ssrf[m*CH+c]*acc[c];
        a = fminf(fmaxf(a,-1.f),1.f);
        xp[((size_t)(b*CM+m))*HW + hw] = a;
    }
}

// ---------------- 3a) stats stage 1 ---------------------------------------------------
__global__ void k_stats1(const float* __restrict__ xp, const float* __restrict__ y,
                         float2* __restrict__ part, int NB){
    int bid = blockIdx.x;
    int p = bid >> 6, c = bid & 63;
    const float* src = (p<3*NB) ? (xp + (size_t)p*HW) : (y + (size_t)(p-3*NB)*HW);
    const float4* s4 = (const float4*)(src + c*1024);
    float4 v = s4[threadIdx.x];
    float s  = v.x + v.y + v.z + v.w;
    float ss = v.x*v.x + v.y*v.y + v.z*v.z + v.w*v.w;
    #pragma unroll
    for(int t=1;t<64;t<<=1){ s += __shfl_xor(s,t); ss += __shfl_xor(ss,t); }
    __shared__ float rs[4], rss[4];
    int wid = threadIdx.x>>6, lane = threadIdx.x&63;
    if(lane==0){ rs[wid]=s; rss[wid]=ss; }
    __syncthreads();
    if(threadIdx.x==0){
        part[bid] = float2{rs[0]+rs[1]+rs[2]+rs[3], rss[0]+rss[1]+rss[2]+rss[3]};
    }
}

// ---------------- 3b) stats stage 2 ---------------------------------------------------
__global__ void k_stats2(const float2* __restrict__ part, float* __restrict__ stats){
    int p = blockIdx.x;
    float2 pa = part[p*64 + threadIdx.x];
    float s = pa.x, ss = pa.y;
    #pragma unroll
    for(int t=1;t<64;t<<=1){ s += __shfl_xor(s,t); ss += __shfl_xor(ss,t); }
    if(threadIdx.x==0){
        float mean = s/(float)HW;
        float var = (ss - s*s/(float)HW) / (float)(HW-1);
        stats[p*2]   = mean;
        stats[p*2+1] = sqrtf(fmaxf(var,0.f));
    }
}

// ---------------- 4) fused SSIM (align + 2D gaussian + difficulty) --------------------
__global__ __launch_bounds__(256) void k_ssim(const float* __restrict__ xp,
                                              const float* __restrict__ y,
                                              const float* __restrict__ stats,
                                              float* __restrict__ diff,
                                              u16* __restrict__ regin, int NB){
    __shared__ float sxa[1600];
    __shared__ float sy2[1600];
    __shared__ float hs[5][1280];
    int t = threadIdx.x;
    int bid = blockIdx.x;
    int bb = bid >> 6;
    int s2 = bid & 63;
    int tx = s2 & 7, ty = s2 >> 3;
    float g[9]; float gs = 0.f;
    #pragma unroll
    for(int k=0;k<9;k++){ float cc=(float)(k-4); g[k]=expf(-cc*cc/4.5f); gs+=g[k]; }
    float ginv = 1.f/gs;
    #pragma unroll
    for(int k=0;k<9;k++) g[k] *= ginv;

    float msum[4] = {0.f,0.f,0.f,0.f};
    for(int m=0;m<3;m++){
        int plane = bb*3+m;
        float sm = stats[plane*2],        ssd = stats[plane*2+1];
        float rm = stats[(plane+3*NB)*2], rsd = stats[(plane+3*NB)*2+1];
        const float* xpp = xp + (size_t)plane*HW;
        const float* yp  = y  + (size_t)plane*HW;
        if(m) __syncthreads();
        #pragma unroll
        for(int it=0; it<7; ++it){
            int s = it*256 + t;
            if(s < 1600){
                int rr = s/40, cc = s - rr*40;
                int gy = ty*32-4+rr, gx = tx*32-4+cc;
                float xv=0.f, yv=0.f;
                if(((unsigned)gy<256u)&&((unsigned)gx<256u)){
                    float v = xpp[(gy<<8)+gx];
                    v = (v-sm)/(ssd+1e-6f)*rsd + rm;
                    xv = fminf(fmaxf(v,-1.f),1.f);
                    yv = yp[(gy<<8)+gx];
                }
                sxa[s]=xv; sy2[s]=yv;
            }
        }
        __syncthreads();
        #pragma unroll
        for(int it=0; it<5; ++it){
            int s = it*256 + t;
            int rr = s>>5, cc = s&31;
            int base = rr*40 + cc;
            float s0=0,s1=0,s2v=0,s3=0,s4=0;
            #pragma unroll
            for(int k=0;k<9;k++){
                float gg=g[k];
                float a=sxa[base+k], b=sy2[base+k];
                s0+=gg*a; s1+=gg*b; s2v+=gg*a*a; s3+=gg*b*b; s4+=gg*a*b;
            }
            hs[0][s]=s0; hs[1][s]=s1; hs[2][s]=s2v; hs[3][s]=s3; hs[4][s]=s4;
        }
        __syncthreads();
        #pragma unroll
        for(int it=0; it<4; ++it){
            int s = it*256 + t;
            int rr = s>>5, cc = s&31;
            float v0=0,v1=0,v2=0,v3=0,v4=0;
            #pragma unroll
            for(int k=0;k<9;k++){
                float gg=g[k];
                int idx=(rr+k)*32+cc;
                v0+=gg*hs[0][idx]; v1+=gg*hs[1][idx]; v2+=gg*hs[2][idx];
                v3+=gg*hs[3][idx]; v4+=gg*hs[4][idx];
            }
            float mu1=v0, mu2=v1;
            float mu1s=mu1*mu1, mu2s=mu2*mu2, mu12=mu1*mu2;
            float sg1=v2-mu1s, sg2=v3-mu2s, sg12=v4-mu12;
            msum[it] += (2.f*mu12+C1S)*(2.f*sg12+C2S)
                      / ((mu1s+mu2s+C1S)*(sg1+sg2+C2S));
        }
    }
    #pragma unroll
    for(int it=0; it<4; ++it){
        int s = it*256 + t;
        int rr = s>>5, cc = s&31;
        int pixg = (bb<<16) + ((ty*32+rr)<<8) + (tx*32+cc);
        float d = fminf(fmaxf((1.f-msum[it]*(1.f/3.f))*0.5f,0.f),1.f);
        diff[pixg] = d;
        regin[(size_t)pixg*REGC + 281] = f2b(d);
    }
}

// ---------------- 7) q,k 1x1 convs -> regin bf16 (32 px per block) --------------------
__global__ __launch_bounds__(128) void k_qk(const u16* __restrict__ x31,
                     const float* __restrict__ y,
                     const float* __restrict__ qw, const float* __restrict__ qb,
                     const float* __restrict__ kw, const float* __restrict__ kb,
                     u16* __restrict__ regin){
    __shared__ float sqw[CE*CH];
    __shared__ float skw[CE*CM];
    __shared__ float sqb[CE], skb[CE];
    for(int i=threadIdx.x;i<CE*CH;i+=128) sqw[i]=qw[i];
    for(int i=threadIdx.x;i<CE*CM;i+=128) skw[i]=kw[i];
    if(threadIdx.x<CE){ sqb[threadIdx.x]=qb[threadIdx.x]; skb[threadIdx.x]=kb[threadIdx.x]; }
    __syncthreads();
    int co = threadIdx.x;
    int p0 = blockIdx.x*32;
    float wk0 = skw[co*CM+0], wk1 = skw[co*CM+1], wk2 = skw[co*CM+2];
    for(int pp=0;pp<32;pp++){
        int pixg = p0+pp;
        int b = pixg>>16, hw = pixg&65535;
        const u16* xr = x31 + (size_t)pixg*32;
        float acc = sqb[co];
        #pragma unroll
        for(int c=0;c<CH;c++) acc += sqw[co*CH+c]*b1f(xr[c]);
        u16* rg = regin + (size_t)pixg*REGC;
        rg[co] = f2b(acc);
        float ack = skb[co] + wk0*y[((size_t)(b*CM  ))*HW+hw]
                            + wk1*y[((size_t)(b*CM+1))*HW+hw]
                            + wk2*y[((size_t)(b*CM+2))*HW+hw];
        rg[128+co] = f2b(ack);
        if(co<6) rg[282+co] = 0;
    }
}

// ---------------- 9) correlation volume: LDS-staged K + fused norms (R14) -------------
// Block: 32x4 px tile, 256 thr (lane-pair per px). Halo 36x8 = 288 px x 256B = 73.7KB
// -> 2 workgroups/CU.
__global__ __launch_bounds__(256) void k_corr(const u16* __restrict__ regin,
                                              u16* __restrict__ regout){
    __shared__ uint4 klv[288*16];      // 73,728 B
    __shared__ float kinvl[288];       // 1,152 B
    int t = threadIdx.x;
    int half = t & 1, pidx = t >> 1;           // 128 px per block
    int bid = blockIdx.x;
    int bb = bid >> 9;                          // batch
    int s2 = bid & 511;
    int tx = s2 & 7, ty = s2 >> 3;              // 8 x 64 tiles of 32x4
    int lw = pidx & 31, lh = pidx >> 5;
    int w = tx*32 + lw;
    int h = ty*4 + lh;
    int pixg = (bb<<16) + (h<<8) + w;

    // stage K halo region (edge clamp baked in), swizzled uint4 slots
    #pragma unroll
    for(int it=0; it<18; ++it){
        int s = it*256 + t;                     // 288*16 = 4608 slots
        int rpx = s >> 4, g = s & 15;
        int rr = rpx/36, cc = rpx - rr*36;
        int gy = min(max(ty*4-2+rr,0),255);
        int gx = min(max(tx*32-2+cc,0),255);
        const uint4* src = (const uint4*)(regin + ((size_t)((bb<<16)+(gy<<8)+gx))*REGC + 128);
        klv[rpx*16 + (g ^ (rpx&15))] = src[g];
    }
    __syncthreads();

    // kinv from staged K: 576 (px,half) items, pair-shfl combine
    #pragma unroll
    for(int it=0; it<3; ++it){
        int item = it*256 + t;
        int px = item>>1, hf = item&1;
        float s = 0.f;
        if(item < 576){
            const uint4* kp = &klv[px*16];
            int sw = px & 15;
            #pragma unroll
            for(int i=0;i<8;i++){
                uint4 kv = kp[(hf*8+i)^sw];
                s += blo(kv.x)*blo(kv.x)+bhi(kv.x)*bhi(kv.x)
                   + blo(kv.y)*blo(kv.y)+bhi(kv.y)*bhi(kv.y)
                   + blo(kv.z)*blo(kv.z)+bhi(kv.z)*bhi(kv.z)
                   + blo(kv.w)*blo(kv.w)+bhi(kv.w)*bhi(kv.w);
            }
        }
        float so = s + __shfl_xor(s,1);
        if(item < 576 && hf==0) kinvl[px] = 1.f/fmaxf(sqrtf(so),1e-12f);
    }
    __syncthreads();

    uint4 q[8];
    const uint4* qp = (const uint4*)(regin + (size_t)pixg*REGC) + half*8;
    #pragma unroll
    for(int i=0;i<8;i++) q[i] = qp[i];
    float sq = 0.f;
    #pragma unroll
    for(int i=0;i<8;i++){
        uint4 v = q[i];
        sq += blo(v.x)*blo(v.x)+bhi(v.x)*bhi(v.x) + blo(v.y)*blo(v.y)+bhi(v.y)*bhi(v.y)
            + blo(v.z)*blo(v.z)+bhi(v.z)*bhi(v.z) + blo(v.w)*blo(v.w)+bhi(v.w)*bhi(v.w);
    }
    sq += __shfl_xor(sq, 1);
    float qn = 1.f/fmaxf(sqrtf(sq),1e-12f);

    float res[13];
    #pragma unroll
    for(int dy=-2;dy<=2;dy++){
        #pragma unroll
        for(int dx=-2;dx<=2;dx++){
            int rpx = (lh+2+dy)*36 + (lw+2+dx);
            const uint4* kp = &klv[rpx*16];
            int sw = rpx & 15;
            float s = 0.f;
            #pragma unroll
            for(int i=0;i<8;i++){
                uint4 kv = kp[(half*8 + i) ^ sw];
                uint4 qv = q[i];
                s += blo(qv.x)*blo(kv.x) + bhi(qv.x)*bhi(kv.x);
                s += blo(qv.y)*blo(kv.y) + bhi(qv.y)*bhi(kv.y);
                s += blo(qv.z)*blo(kv.z) + bhi(qv.z)*bhi(kv.z);
                s += blo(qv.w)*blo(kv.w) + bhi(qv.w)*bhi(kv.w);
            }
            s += __shfl_xor(s, 1);
            float cv = s*qn*kinvl[rpx];
            int o = (dy+2)*5 + (dx+2);
            if(o < 13){ if(half==0) res[o] = cv; }
            else      { if(half==1) res[o-13] = cv; }
        }
    }

    u16* rg = regout + (size_t)pixg*REGC + 256;
    if(half==0){
        u16 p[13];
        #pragma unroll
        for(int i=0;i<13;i++) p[i] = f2b(res[i]);
        uint4 v0; u32* v0p = (u32*)&v0;
        #pragma unroll
        for(int i=0;i<4;i++) v0p[i] = (u32)p[2*i] | ((u32)p[2*i+1]<<16);
        *(uint4*)(rg) = v0;
        *(u32*)(rg+8)  = (u32)p[8]  | ((u32)p[9]<<16);
        *(u32*)(rg+10) = (u32)p[10] | ((u32)p[11]<<16);
        rg[12] = p[12];
    } else {
        u16 p[12];
        #pragma unroll
        for(int i=0;i<12;i++) p[i] = f2b(res[i]);
        rg[13] = p[0];
        *(u32*)(rg+14) = (u32)p[1] | ((u32)p[2]<<16);
        uint4 v1; u32* v1p = (u32*)&v1;
        #pragma unroll
        for(int i=0;i<4;i++) v1p[i] = (u32)p[3+2*i] | ((u32)p[4+2*i]<<16);
        *(uint4*)(rg+16) = v1;
        rg[24] = p[11];
    }
}

// ---------------- 10) weight rearrange + zpad clear -----------------------------------
__global__ void k_wre(const float* __restrict__ w1, const float* __restrict__ w2,
                      u16* __restrict__ w1f, u16* __restrict__ w2f,
                      u16* __restrict__ zpad){
    int i = blockIdx.x*256 + threadIdx.x;
    if(i < 32) zpad[i] = 0;
    if(i < 9*9*128*32){
        int j = i & 7;
        int gg = (i>>3)&3;
        int co = (i>>5)&127;
        int rest = i>>12;
        int kbg = rest%9, tap = rest/9;
        int ci = kbg*32 + gg*8 + j;
        float v = (ci<282) ? w1[((size_t)co*282 + ci)*9 + tap] : 0.f;
        w1f[i] = f2b(v);
    }
    if(i < 9*4*64*32){
        int j = i & 7;
        int gg = (i>>3)&3;
        int co = (i>>5)&63;
        int rest = i>>11;
        int kbg = rest&3, tap = rest>>2;
        int ci = kbg*32 + gg*8 + j;
        w2f[i] = f2b(w2[((size_t)co*128 + ci)*9 + tap]);
    }
}

// ---------------- 11+12) MFMA 3x3 conv (implicit GEMM over taps) ----------------------
template<int MF>
__device__ __forceinline__ void ldaM(const uint4* sbuf, int ky, int kx, int kb,
                                     int lane15, int lgrp, bf16x8* ar){
    #pragma unroll
    for(int mf=0;mf<MF;mf++){
        int spx  = (mf&1)*16 + lane15 + kx;
        int srow = (mf>>1) + ky;
        int slot = (srow*34 + spx)*8 + ((kb*4 + lgrp) ^ (spx&7));
        ar[mf] = *(const bf16x8*)&sbuf[slot];
    }
}

template<int NF, int KBGT, int NCO>
__device__ __forceinline__ void ldbN(const u16* __restrict__ wf, int kbg, int tap,
                                     int co0, int lane15, int lgrp, bf16x8* br){
    #pragma unroll
    for(int nf=0;nf<NF;nf++){
        size_t idx = ((size_t)((tap*KBGT + kbg)*NCO + co0 + nf*16 + lane15))*4 + lgrp;
        br[nf] = *(const bf16x8*)(wf + idx*8);
    }
}

template<int MF, int NF, int KBGT, int NCO, int KBI>
__device__ __forceinline__ void conv_steps(const uint4* sbuf, const u16* __restrict__ wf,
                                           int kbgbase, int co0, int lane15, int lgrp,
                                           f32x4 (&acc)[MF][NF]){
    constexpr int NST = 9*KBI;
    #pragma unroll
    for(int s=0;s<NST;s++){
        int ky,kx,kb;
        if(KBI==2){ ky = s/6; kx = (s>>1)%3; kb = s&1; }
        else      { ky = s/3; kx = s%3;      kb = 0;   }
        bf16x8 a[MF];
        bf16x8 b[NF];
        ldaM<MF>(sbuf, ky,kx,kb, lane15, lgrp, a);
        ldbN<NF,KBGT,NCO>(wf, kbgbase+kb, ky*3+kx, co0, lane15, lgrp, b);
        #pragma unroll
        for(int mf=0;mf<MF;mf++)
            #pragma unroll
            for(int nf=0;nf<NF;nf++)
                acc[mf][nf] = mfma16(a[mf], b[nf], acc[mf][nf]);
    }
}

template<int CSTRIDE, int CINTOT, int NCO, int KBGT, int TM>
__global__ __launch_bounds__(128, 1) void k_conv3(const u16* __restrict__ in,
                                                  const u16* __restrict__ wf,
                                                  const float* __restrict__ bias,
                                                  u16* __restrict__ out,
                                                  const u16* __restrict__ zpad){
    constexpr int NW = 2;
    constexpr int NF = NCO/(16*NW);
    constexpr int MF = 2*TM;
    constexpr int NCHUNK = (CINTOT + 63)/64;
    constexpr int NTH = NW*64;
    constexpr int SLOTS = (TM+2)*34*8;
    __shared__ uint4 sT[2*SLOTS];
    int t = threadIdx.x;
    int lane15 = t & 15, lgrp = (t >> 4) & 3;
    int co0 = (t >> 6) * (NCO/NW);
    int rb = blockIdx.x;
    int bid = (rb & 7)*(gridDim.x >> 3) + (rb >> 3);
    int bb = bid >> 9;
    int s2 = bid & 511;
    int tx = s2 & 7, ty = s2 >> 3;
    int row0 = ty*TM, col0 = tx*32;
    const u16* inb  = in  + (size_t)bb*HW*CSTRIDE;
    u16*       outb = out + (size_t)bb*HW*NCO;

    f32x4 acc[MF][NF];
    #pragma unroll
    for(int nf=0;nf<NF;nf++){
        float bsv = bias[co0 + nf*16 + lane15];
        #pragma unroll
        for(int mf=0;mf<MF;mf++) acc[mf][nf] = f32x4{bsv,bsv,bsv,bsv};
    }

    auto stage = [&](int buf, int kc){
        constexpr int NIT = (SLOTS + NTH - 1)/NTH;
        #pragma unroll
        for(int it=0; it<NIT; ++it){
            int s = it*NTH + t;
            if(s >= SLOTS) continue;
            int srow = s/272, rem = s - srow*272;
            int spx = rem>>3, ggp = rem&7;
            int gg = ggp ^ (spx&7);
            int gy = row0-1+srow, gx = col0-1+spx;
            bool ok = ((unsigned)gy<256u) && ((unsigned)gx<256u);
            const u16* src = ok ? (inb + (size_t)((gy<<8)+gx)*CSTRIDE + kc + gg*8) : zpad;
            __builtin_amdgcn_global_load_lds(
                (const __attribute__((address_space(1))) u32*)src,
                (__attribute__((address_space(3))) u32*)&sT[buf*SLOTS + s],
                16, 0, 0);
        }
    };

    stage(0, 0);
    __syncthreads();

    int cur = 0;
    for(int j=0;j<NCHUNK;j++){
        if(j+1 < NCHUNK) stage(cur^1, (j+1)*64);
        if(CINTOT==288 && j==NCHUNK-1)
            conv_steps<MF,NF,KBGT,NCO,1>(&sT[cur*SLOTS], wf, j*2, co0, lane15, lgrp, acc);
        else
            conv_steps<MF,NF,KBGT,NCO,2>(&sT[cur*SLOTS], wf, j*2, co0, lane15, lgrp, acc);
        if(j+1 < NCHUNK){
            __syncthreads();
            cur ^= 1;
        }
    }

    #pragma unroll
    for(int mf=0;mf<MF;mf++){
        int prow  = row0 + (mf>>1);
        int pcolb = col0 + (mf&1)*16 + lgrp*4;
        #pragma unroll
        for(int nf=0;nf<NF;nf++){
            int co = co0 + nf*16 + lane15;
            #pragma unroll
            for(int r=0;r<4;r++){
                int pix = (prow<<8) + pcolb + r;
                float v = acc[mf][nf][r];
                v = (v>0.f) ? v : 0.2f*v;
                outb[(size_t)pix*NCO + co] = f2b(v);
            }
        }
    }
}

// ---------------- 13) flow (1x1 conv + tanh) + bilinear warp --------------------------
__device__ __forceinline__ float reflectc(float coord, float size){
    float c = fabsf(coord + 0.5f);
    float extra = fmodf(c, size);
    float flips = floorf(c/size);
    float fo = fmodf(flips, 2.0f);
    float r = (fo == 0.0f) ? (extra - 0.5f) : (size - extra - 0.5f);
    return fminf(fmaxf(r, 0.0f), size - 1.0f);
}

__global__ void k_flowwarp(const u16* __restrict__ h2, const float* __restrict__ w3,
                           const float* __restrict__ b3, const float* __restrict__ diff,
                           const u16* __restrict__ x31, float* __restrict__ out){
    __shared__ float sw[130];
    for(int i=threadIdx.x;i<128;i+=256) sw[i]=w3[i];
    if(threadIdx.x<2) sw[128+threadIdx.x]=b3[threadIdx.x];
    __syncthreads();
    int pixg = blockIdx.x*256 + threadIdx.x;
    int b = pixg>>16, hw = pixg&65535, h = hw>>8, w = hw&255;
    const uint4* h4 = (const uint4*)(h2 + (size_t)pixg*64);
    float f0 = sw[128], f1 = sw[129];
    #pragma unroll
    for(int cc=0;cc<8;cc++){
        uint4 u = h4[cc];
        float vv[8] = {blo(u.x),bhi(u.x),blo(u.y),bhi(u.y),blo(u.z),bhi(u.z),blo(u.w),bhi(u.w)};
        #pragma unroll
        for(int j=0;j<8;j++){ int c = cc*8+j; f0 += sw[c]*vv[j]; f1 += sw[64+c]*vv[j]; }
    }
    float d = diff[pixg];
    f0 = tanhf(f0)*2.0f*d;
    f1 = tanhf(f1)*2.0f*d;
    float ix = reflectc((float)w + f0, 256.f);
    float iy = reflectc((float)h + f1, 256.f);
    float x0 = floorf(ix), y0 = floorf(iy);
    float wx = ix-x0, wy = iy-y0;
    int x0i = min(max((int)x0,0),255);
    int x1i = min(x0i+1,255);
    int y0i = min(max((int)y0,0),255);
    int y1i = min(y0i+1,255);
    const u16* p00 = x31 + ((size_t)((b<<16)+(y0i<<8)+x0i))*32;
    const u16* p01 = x31 + ((size_t)((b<<16)+(y0i<<8)+x1i))*32;
    const u16* p10 = x31 + ((size_t)((b<<16)+(y1i<<8)+x0i))*32;
    const u16* p11 = x31 + ((size_t)((b<<16)+(y1i<<8)+x1i))*32;
    float w00=(1.f-wy)*(1.f-wx), w01=(1.f-wy)*wx, w10=wy*(1.f-wx), w11=wy*wx;
    float* ob = out + (size_t)b*CH*HW + hw;
    #pragma unroll
    for(int c=0;c<CH;c++){
        ob[(size_t)c*HW] = w00*b1f(p00[c]) + w01*b1f(p01[c])
                         + w10*b1f(p10[c]) + w11*b1f(p11[c]);
    }
}

extern "C" void kernel_launch(void* const* d_in, const int* in_sizes, int n_in,
                              void* d_out, int out_size, void* d_ws, size_t ws_size,
                              hipStream_t stream) {
    const float* x    = (const float*)d_in[0];
    const float* y    = (const float*)d_in[1];
    const float* srf  = (const float*)d_in[2];
    const float* chw  = (const float*)d_in[3];
    const float* chb  = (const float*)d_in[4];
    const float* qw   = (const float*)d_in[5];
    const float* qb   = (const float*)d_in[6];
    const float* kw   = (const float*)d_in[7];
    const float* kb   = (const float*)d_in[8];
    const float* w1   = (const float*)d_in[9];
    const float* b1p  = (const float*)d_in[10];
    const float* w2   = (const float*)d_in[11];
    const float* b2p  = (const float*)d_in[12];
    const float* w3   = (const float*)d_in[13];
    const float* b3p  = (const float*)d_in[14];

    struct Arena {
        u16 *x31, *regin, *h1, *h2, *w1f, *w2f, *zpad;
        float *xp, *stats, *diff;
        float2 *part;
    };
    auto layout = [&](char* base, int G, Arena* A)->size_t{
        size_t o = 0;
        auto take = [&](size_t sz)->char*{ char* p = base ? base+o : 0; o += (sz+255)&~255ull; return p; };
        Arena tmpA; Arena* P = A ? A : &tmpA;
        P->x31   = (u16*)  take((size_t)G*HW*32*2);
        P->xp    = (float*)take((size_t)G*3*HW*4);
        P->stats = (float*)take(6*4*2*4);
        P->part  = (float2*)take((size_t)6*4*64*8);
        P->diff  = (float*)take((size_t)G*HW*4);
        P->regin = (u16*)  take((size_t)G*HW*REGC*2);
        P->h1    = (u16*)  take((size_t)G*HW*128*2);
        P->h2    = (u16*)  take((size_t)G*HW*64*2);
        P->w1f   = (u16*)  take((size_t)9*9*128*32*2);
        P->w2f   = (u16*)  take((size_t)9*4*64*32*2);
        P->zpad  = (u16*)  take(64);
        return o;
    };

    int G = 4;
    while(G > 1 && layout(nullptr, G, nullptr) > ws_size) G >>= 1;
    Arena A;
    layout((char*)d_ws, G, &A);

    k_wre<<<1296, 256, 0, stream>>>(w1, w2, A.w1f, A.w2f, A.zpad);

    for(int g0=0; g0<4; g0+=G){
        int NB = G;
        const float* xg  = x + (size_t)g0*CIN2*HW;
        const float* yg  = y + (size_t)g0*CM*HW;
        float* outg      = (float*)d_out + (size_t)g0*CH*HW;

        k_conv_half<<<NB*256,  256, 0, stream>>>(xg, chw, chb, srf, A.x31, A.xp);
        k_stats1   <<<NB*384,  256, 0, stream>>>(A.xp, yg, A.part, NB);
        k_stats2   <<<NB*6,     64, 0, stream>>>(A.part, A.stats);
        k_ssim     <<<NB*64,   256, 0, stream>>>(A.xp, yg, A.stats, A.diff, A.regin, NB);
        k_qk       <<<NB*2048, 128, 0, stream>>>(A.x31, yg, qw, qb, kw, kb, A.regin);
        k_corr     <<<NB*512,  256, 0, stream>>>(A.regin, A.regin);
        k_conv3<288,288,128,9,4><<<NB*512, 128, 0, stream>>>(A.regin, A.w1f, b1p, A.h1, A.zpad);
        k_conv3<128,128, 64,4,4><<<NB*512, 128, 0, stream>>>(A.h1, A.w2f, b2p, A.h2, A.zpad);
        k_flowwarp <<<NB*256,  256, 0, stream>>>(A.h2, w3, b3p, A.diff, A.x31, outg);
    }
}

// Round 17
// 644.479 us; speedup vs baseline: 1.3300x; 1.1091x over previous
//
#include <hip/hip_runtime.h>
#include <hip/hip_bf16.h>
#include <math.h>

// R17: r2 conv + flow(1x1+tanh) + bilinear warp fused into one kernel.
// r2's 4x32 tile = 128 px = 1 px/thread; h2 lives only in LDS (XOR-swizzled
// 16B groups). Deletes k_flowwarp + the 33.6MB h2 buffer (67MB traffic).
// Conv cores, corr (R14), ssim, qk, conv_half+project all unchanged.

#define HH 256
#define WWI 256
#define HW 65536
#define CH 31
#define CIN2 62
#define CM 3
#define CE 128
#define REGC 288
#define C1S 1e-4f
#define C2S 9e-4f

typedef unsigned short u16;
typedef unsigned int u32;
typedef short bf16x8 __attribute__((ext_vector_type(8)));
typedef float f32x4 __attribute__((ext_vector_type(4)));

__device__ __forceinline__ float blo(u32 u){ return __uint_as_float(u << 16); }
__device__ __forceinline__ float bhi(u32 u){ return __uint_as_float(u & 0xffff0000u); }
__device__ __forceinline__ float b1f(u16 u){ return __uint_as_float(((u32)u) << 16); }
__device__ __forceinline__ u16 f2b(float f){
    u32 u = __float_as_uint(f);
    u32 r = (u + 0x7fffu + ((u >> 16) & 1u)) >> 16;
    return (u16)r;
}
__device__ __forceinline__ f32x4 mfma16(bf16x8 a, bf16x8 b, f32x4 c){
    return __builtin_amdgcn_mfma_f32_16x16x32_bf16(a, b, c, 0, 0, 0);
}
__device__ __forceinline__ float reflectc(float coord, float size){
    float c = fabsf(coord + 0.5f);
    float extra = fmodf(c, size);
    float flips = floorf(c/size);
    float fo = fmodf(flips, 2.0f);
    float r = (fo == 0.0f) ? (extra - 0.5f) : (size - extra - 0.5f);
    return fminf(fmaxf(r, 0.0f), size - 1.0f);
}

// ---------------- 1) conv_half + project fused --------------------------------------
__global__ void k_conv_half(const float* __restrict__ x, const float* __restrict__ w,
                            const float* __restrict__ bias, const float* __restrict__ srf,
                            u16* __restrict__ x31, float* __restrict__ xp){
    __shared__ float sw[CH*CIN2];
    __shared__ float sb[CH+1];
    __shared__ float ssrf[CM*CH];
    for(int i=threadIdx.x;i<CH*CIN2;i+=256) sw[i]=w[i];
    for(int i=threadIdx.x;i<CH;i+=256) sb[i]=bias[i];
    for(int i=threadIdx.x;i<CM*CH;i+=256) ssrf[i]=srf[i];
    __syncthreads();
    int pixg = blockIdx.x*256 + threadIdx.x;
    int b = pixg>>16, hw = pixg&65535;
    float acc[CH];
    #pragma unroll
    for(int c=0;c<CH;c++) acc[c]=sb[c];
    for(int ci=0;ci<CIN2;ci++){
        float xv = x[((size_t)(b*CIN2+ci))*HW + hw];
        #pragma unroll
        for(int c=0;c<CH;c++) acc[c] += sw[c*CIN2+ci]*xv;
    }
    u16* o = x31 + (size_t)pixg*32;
    #pragma unroll
    for(int c=0;c<CH;c++) o[c]=f2b(acc[c]);
    o[31]=0;
    #pragma unroll
    for(int m=0;m<CM;m++){
        float a=0.f;
        #pragma unroll
        for(int c=0;c<CH;c++) a += ssrf[m*CH+c]*acc[c];
        a = fminf(fmaxf(a,-1.f),1.f);
        xp[((size_t)(b*CM+m))*HW + hw] = a;
    }
}

// ---------------- 3a) stats stage 1 ---------------------------------------------------
__global__ void k_stats1(const float* __restrict__ xp, const float* __restrict__ y,
                         float2* __restrict__ part, int NB){
    int bid = blockIdx.x;
    int p = bid >> 6, c = bid & 63;
    const float* src = (p<3*NB) ? (xp + (size_t)p*HW) : (y + (size_t)(p-3*NB)*HW);
    const float4* s4 = (const float4*)(src + c*1024);
    float4 v = s4[threadIdx.x];
    float s  = v.x + v.y + v.z + v.w;
    float ss = v.x*v.x + v.y*v.y + v.z*v.z + v.w*v.w;
    #pragma unroll
    for(int t=1;t<64;t<<=1){ s += __shfl_xor(s,t); ss += __shfl_xor(ss,t); }
    __shared__ float rs[4], rss[4];
    int wid = threadIdx.x>>6, lane = threadIdx.x&63;
    if(lane==0){ rs[wid]=s; rss[wid]=ss; }
    __syncthreads();
    if(threadIdx.x==0){
        part[bid] = float2{rs[0]+rs[1]+rs[2]+rs[3], rss[0]+rss[1]+rss[2]+rss[3]};
    }
}

// ---------------- 3b) stats stage 2 ---------------------------------------------------
__global__ void k_stats2(const float2* __restrict__ part, float* __restrict__ stats){
    int p = blockIdx.x;
    float2 pa = part[p*64 + threadIdx.x];
    float s = pa.x, ss = pa.y;
    #pragma unroll
    for(int t=1;t<64;t<<=1){ s += __shfl_xor(s,t); ss += __shfl_xor(ss,t); }
    if(threadIdx.x==0){
        float mean = s/(float)HW;
        float var = (ss - s*s/(float)HW) / (float)(HW-1);
        stats[p*2]   = mean;
        stats[p*2+1] = sqrtf(fmaxf(var,0.f));
    }
}

// ---------------- 4) fused SSIM (align + 2D gaussian + difficulty) --------------------
__global__ __launch_bounds__(256) void k_ssim(const float* __restrict__ xp,
                                              const float* __restrict__ y,
                                              const float* __restrict__ stats,
                                              float* __restrict__ diff,
                                              u16* __restrict__ regin, int NB){
    __shared__ float sxa[1600];
    __shared__ float sy2[1600];
    __shared__ float hs[5][1280];
    int t = threadIdx.x;
    int bid = blockIdx.x;
    int bb = bid >> 6;
    int s2 = bid & 63;
    int tx = s2 & 7, ty = s2 >> 3;
    float g[9]; float gs = 0.f;
    #pragma unroll
    for(int k=0;k<9;k++){ float cc=(float)(k-4); g[k]=expf(-cc*cc/4.5f); gs+=g[k]; }
    float ginv = 1.f/gs;
    #pragma unroll
    for(int k=0;k<9;k++) g[k] *= ginv;

    float msum[4] = {0.f,0.f,0.f,0.f};
    for(int m=0;m<3;m++){
        int plane = bb*3+m;
        float sm = stats[plane*2],        ssd = stats[plane*2+1];
        float rm = stats[(plane+3*NB)*2], rsd = stats[(plane+3*NB)*2+1];
        const float* xpp = xp + (size_t)plane*HW;
        const float* yp  = y  + (size_t)plane*HW;
        if(m) __syncthreads();
        #pragma unroll
        for(int it=0; it<7; ++it){
            int s = it*256 + t;
            if(s < 1600){
                int rr = s/40, cc = s - rr*40;
                int gy = ty*32-4+rr, gx = tx*32-4+cc;
                float xv=0.f, yv=0.f;
                if(((unsigned)gy<256u)&&((unsigned)gx<256u)){
                    float v = xpp[(gy<<8)+gx];
                    v = (v-sm)/(ssd+1e-6f)*rsd + rm;
                    xv = fminf(fmaxf(v,-1.f),1.f);
                    yv = yp[(gy<<8)+gx];
                }
                sxa[s]=xv; sy2[s]=yv;
            }
        }
        __syncthreads();
        #pragma unroll
        for(int it=0; it<5; ++it){
            int s = it*256 + t;
            int rr = s>>5, cc = s&31;
            int base = rr*40 + cc;
            float s0=0,s1=0,s2v=0,s3=0,s4=0;
            #pragma unroll
            for(int k=0;k<9;k++){
                float gg=g[k];
                float a=sxa[base+k], b=sy2[base+k];
                s0+=gg*a; s1+=gg*b; s2v+=gg*a*a; s3+=gg*b*b; s4+=gg*a*b;
            }
            hs[0][s]=s0; hs[1][s]=s1; hs[2][s]=s2v; hs[3][s]=s3; hs[4][s]=s4;
        }
        __syncthreads();
        #pragma unroll
        for(int it=0; it<4; ++it){
            int s = it*256 + t;
            int rr = s>>5, cc = s&31;
            float v0=0,v1=0,v2=0,v3=0,v4=0;
            #pragma unroll
            for(int k=0;k<9;k++){
                float gg=g[k];
                int idx=(rr+k)*32+cc;
                v0+=gg*hs[0][idx]; v1+=gg*hs[1][idx]; v2+=gg*hs[2][idx];
                v3+=gg*hs[3][idx]; v4+=gg*hs[4][idx];
            }
            float mu1=v0, mu2=v1;
            float mu1s=mu1*mu1, mu2s=mu2*mu2, mu12=mu1*mu2;
            float sg1=v2-mu1s, sg2=v3-mu2s, sg12=v4-mu12;
            msum[it] += (2.f*mu12+C1S)*(2.f*sg12+C2S)
                      / ((mu1s+mu2s+C1S)*(sg1+sg2+C2S));
        }
    }
    #pragma unroll
    for(int it=0; it<4; ++it){
        int s = it*256 + t;
        int rr = s>>5, cc = s&31;
        int pixg = (bb<<16) + ((ty*32+rr)<<8) + (tx*32+cc);
        float d = fminf(fmaxf((1.f-msum[it]*(1.f/3.f))*0.5f,0.f),1.f);
        diff[pixg] = d;
        regin[(size_t)pixg*REGC + 281] = f2b(d);
    }
}

// ---------------- 7) q,k 1x1 convs -> regin bf16 (32 px per block) --------------------
__global__ __launch_bounds__(128) void k_qk(const u16* __restrict__ x31,
                     const float* __restrict__ y,
                     const float* __restrict__ qw, const float* __restrict__ qb,
                     const float* __restrict__ kw, const float* __restrict__ kb,
                     u16* __restrict__ regin){
    __shared__ float sqw[CE*CH];
    __shared__ float skw[CE*CM];
    __shared__ float sqb[CE], skb[CE];
    for(int i=threadIdx.x;i<CE*CH;i+=128) sqw[i]=qw[i];
    for(int i=threadIdx.x;i<CE*CM;i+=128) skw[i]=kw[i];
    if(threadIdx.x<CE){ sqb[threadIdx.x]=qb[threadIdx.x]; skb[threadIdx.x]=kb[threadIdx.x]; }
    __syncthreads();
    int co = threadIdx.x;
    int p0 = blockIdx.x*32;
    float wk0 = skw[co*CM+0], wk1 = skw[co*CM+1], wk2 = skw[co*CM+2];
    for(int pp=0;pp<32;pp++){
        int pixg = p0+pp;
        int b = pixg>>16, hw = pixg&65535;
        const u16* xr = x31 + (size_t)pixg*32;
        float acc = sqb[co];
        #pragma unroll
        for(int c=0;c<CH;c++) acc += sqw[co*CH+c]*b1f(xr[c]);
        u16* rg = regin + (size_t)pixg*REGC;
        rg[co] = f2b(acc);
        float ack = skb[co] + wk0*y[((size_t)(b*CM  ))*HW+hw]
                            + wk1*y[((size_t)(b*CM+1))*HW+hw]
                            + wk2*y[((size_t)(b*CM+2))*HW+hw];
        rg[128+co] = f2b(ack);
        if(co<6) rg[282+co] = 0;
    }
}

// ---------------- 9) correlation volume: LDS-staged K + fused norms (R14) -------------
__global__ __launch_bounds__(256) void k_corr(const u16* __restrict__ regin,
                                              u16* __restrict__ regout){
    __shared__ uint4 klv[288*16];      // 73,728 B
    __shared__ float kinvl[288];
    int t = threadIdx.x;
    int half = t & 1, pidx = t >> 1;
    int bid = blockIdx.x;
    int bb = bid >> 9;
    int s2 = bid & 511;
    int tx = s2 & 7, ty = s2 >> 3;
    int lw = pidx & 31, lh = pidx >> 5;
    int w = tx*32 + lw;
    int h = ty*4 + lh;
    int pixg = (bb<<16) + (h<<8) + w;

    #pragma unroll
    for(int it=0; it<18; ++it){
        int s = it*256 + t;
        int rpx = s >> 4, g = s & 15;
        int rr = rpx/36, cc = rpx - rr*36;
        int gy = min(max(ty*4-2+rr,0),255);
        int gx = min(max(tx*32-2+cc,0),255);
        const uint4* src = (const uint4*)(regin + ((size_t)((bb<<16)+(gy<<8)+gx))*REGC + 128);
        klv[rpx*16 + (g ^ (rpx&15))] = src[g];
    }
    __syncthreads();

    #pragma unroll
    for(int it=0; it<3; ++it){
        int item = it*256 + t;
        int px = item>>1, hf = item&1;
        float s = 0.f;
        if(item < 576){
            const uint4* kp = &klv[px*16];
            int sw = px & 15;
            #pragma unroll
            for(int i=0;i<8;i++){
                uint4 kv = kp[(hf*8+i)^sw];
                s += blo(kv.x)*blo(kv.x)+bhi(kv.x)*bhi(kv.x)
                   + blo(kv.y)*blo(kv.y)+bhi(kv.y)*bhi(kv.y)
                   + blo(kv.z)*blo(kv.z)+bhi(kv.z)*bhi(kv.z)
                   + blo(kv.w)*blo(kv.w)+bhi(kv.w)*bhi(kv.w);
            }
        }
        float so = s + __shfl_xor(s,1);
        if(item < 576 && hf==0) kinvl[px] = 1.f/fmaxf(sqrtf(so),1e-12f);
    }
    __syncthreads();

    uint4 q[8];
    const uint4* qp = (const uint4*)(regin + (size_t)pixg*REGC) + half*8;
    #pragma unroll
    for(int i=0;i<8;i++) q[i] = qp[i];
    float sq = 0.f;
    #pragma unroll
    for(int i=0;i<8;i++){
        uint4 v = q[i];
        sq += blo(v.x)*blo(v.x)+bhi(v.x)*bhi(v.x) + blo(v.y)*blo(v.y)+bhi(v.y)*bhi(v.y)
            + blo(v.z)*blo(v.z)+bhi(v.z)*bhi(v.z) + blo(v.w)*blo(v.w)+bhi(v.w)*bhi(v.w);
    }
    sq += __shfl_xor(sq, 1);
    float qn = 1.f/fmaxf(sqrtf(sq),1e-12f);

    float res[13];
    #pragma unroll
    for(int dy=-2;dy<=2;dy++){
        #pragma unroll
        for(int dx=-2;dx<=2;dx++){
            int rpx = (lh+2+dy)*36 + (lw+2+dx);
            const uint4* kp = &klv[rpx*16];
            int sw = rpx & 15;
            float s = 0.f;
            #pragma unroll
            for(int i=0;i<8;i++){
                uint4 kv = kp[(half*8 + i) ^ sw];
                uint4 qv = q[i];
                s += blo(qv.x)*blo(kv.x) + bhi(qv.x)*bhi(kv.x);
                s += blo(qv.y)*blo(kv.y) + bhi(qv.y)*bhi(kv.y);
                s += blo(qv.z)*blo(kv.z) + bhi(qv.z)*bhi(kv.z);
                s += blo(qv.w)*blo(kv.w) + bhi(qv.w)*bhi(kv.w);
            }
            s += __shfl_xor(s, 1);
            float cv = s*qn*kinvl[rpx];
            int o = (dy+2)*5 + (dx+2);
            if(o < 13){ if(half==0) res[o] = cv; }
            else      { if(half==1) res[o-13] = cv; }
        }
    }

    u16* rg = regout + (size_t)pixg*REGC + 256;
    if(half==0){
        u16 p[13];
        #pragma unroll
        for(int i=0;i<13;i++) p[i] = f2b(res[i]);
        uint4 v0; u32* v0p = (u32*)&v0;
        #pragma unroll
        for(int i=0;i<4;i++) v0p[i] = (u32)p[2*i] | ((u32)p[2*i+1]<<16);
        *(uint4*)(rg) = v0;
        *(u32*)(rg+8)  = (u32)p[8]  | ((u32)p[9]<<16);
        *(u32*)(rg+10) = (u32)p[10] | ((u32)p[11]<<16);
        rg[12] = p[12];
    } else {
        u16 p[12];
        #pragma unroll
        for(int i=0;i<12;i++) p[i] = f2b(res[i]);
        rg[13] = p[0];
        *(u32*)(rg+14) = (u32)p[1] | ((u32)p[2]<<16);
        uint4 v1; u32* v1p = (u32*)&v1;
        #pragma unroll
        for(int i=0;i<4;i++) v1p[i] = (u32)p[3+2*i] | ((u32)p[4+2*i]<<16);
        *(uint4*)(rg+16) = v1;
        rg[24] = p[11];
    }
}

// ---------------- 10) weight rearrange + zpad clear -----------------------------------
__global__ void k_wre(const float* __restrict__ w1, const float* __restrict__ w2,
                      u16* __restrict__ w1f, u16* __restrict__ w2f,
                      u16* __restrict__ zpad){
    int i = blockIdx.x*256 + threadIdx.x;
    if(i < 32) zpad[i] = 0;
    if(i < 9*9*128*32){
        int j = i & 7;
        int gg = (i>>3)&3;
        int co = (i>>5)&127;
        int rest = i>>12;
        int kbg = rest%9, tap = rest/9;
        int ci = kbg*32 + gg*8 + j;
        float v = (ci<282) ? w1[((size_t)co*282 + ci)*9 + tap] : 0.f;
        w1f[i] = f2b(v);
    }
    if(i < 9*4*64*32){
        int j = i & 7;
        int gg = (i>>3)&3;
        int co = (i>>5)&63;
        int rest = i>>11;
        int kbg = rest&3, tap = rest>>2;
        int ci = kbg*32 + gg*8 + j;
        w2f[i] = f2b(w2[((size_t)co*128 + ci)*9 + tap]);
    }
}

// ---------------- 11+12) MFMA 3x3 conv; r2 variant fuses flow+warp epilogue -----------
template<int MF>
__device__ __forceinline__ void ldaM(const uint4* sbuf, int ky, int kx, int kb,
                                     int lane15, int lgrp, bf16x8* ar){
    #pragma unroll
    for(int mf=0;mf<MF;mf++){
        int spx  = (mf&1)*16 + lane15 + kx;
        int srow = (mf>>1) + ky;
        int slot = (srow*34 + spx)*8 + ((kb*4 + lgrp) ^ (spx&7));
        ar[mf] = *(const bf16x8*)&sbuf[slot];
    }
}

template<int NF, int KBGT, int NCO>
__device__ __forceinline__ void ldbN(const u16* __restrict__ wf, int kbg, int tap,
                                     int co0, int lane15, int lgrp, bf16x8* br){
    #pragma unroll
    for(int nf=0;nf<NF;nf++){
        size_t idx = ((size_t)((tap*KBGT + kbg)*NCO + co0 + nf*16 + lane15))*4 + lgrp;
        br[nf] = *(const bf16x8*)(wf + idx*8);
    }
}

template<int MF, int NF, int KBGT, int NCO, int KBI>
__device__ __forceinline__ void conv_steps(const uint4* sbuf, const u16* __restrict__ wf,
                                           int kbgbase, int co0, int lane15, int lgrp,
                                           f32x4 (&acc)[MF][NF]){
    constexpr int NST = 9*KBI;
    #pragma unroll
    for(int s=0;s<NST;s++){
        int ky,kx,kb;
        if(KBI==2){ ky = s/6; kx = (s>>1)%3; kb = s&1; }
        else      { ky = s/3; kx = s%3;      kb = 0;   }
        bf16x8 a[MF];
        bf16x8 b[NF];
        ldaM<MF>(sbuf, ky,kx,kb, lane15, lgrp, a);
        ldbN<NF,KBGT,NCO>(wf, kbgbase+kb, ky*3+kx, co0, lane15, lgrp, b);
        #pragma unroll
        for(int mf=0;mf<MF;mf++)
            #pragma unroll
            for(int nf=0;nf<NF;nf++)
                acc[mf][nf] = mfma16(a[mf], b[nf], acc[mf][nf]);
    }
}

template<int CSTRIDE, int CINTOT, int NCO, int KBGT, int TM, int FUSE>
__global__ __launch_bounds__(128, 1) void k_conv3(const u16* __restrict__ in,
                                                  const u16* __restrict__ wf,
                                                  const float* __restrict__ bias,
                                                  u16* __restrict__ out16,
                                                  float* __restrict__ outf,
                                                  const float* __restrict__ w3,
                                                  const float* __restrict__ b3,
                                                  const float* __restrict__ diff,
                                                  const u16* __restrict__ x31,
                                                  const u16* __restrict__ zpad){
    constexpr int NW = 2;
    constexpr int NF = NCO/(16*NW);
    constexpr int MF = 2*TM;
    constexpr int NCHUNK = (CINTOT + 63)/64;
    constexpr int NTH = NW*64;
    constexpr int SLOTS = (TM+2)*34*8;
    __shared__ uint4 sT[2*SLOTS];
    __shared__ float swf[132];
    int t = threadIdx.x;
    int lane15 = t & 15, lgrp = (t >> 4) & 3;
    int co0 = (t >> 6) * (NCO/NW);
    int rb = blockIdx.x;
    int bid = (rb & 7)*(gridDim.x >> 3) + (rb >> 3);
    int bb = bid >> 9;
    int s2 = bid & 511;
    int tx = s2 & 7, ty = s2 >> 3;
    int row0 = ty*TM, col0 = tx*32;
    const u16* inb  = in + (size_t)bb*HW*CSTRIDE;

    if(FUSE){
        if(t < 128) swf[t] = w3[t];
        if(t < 2)   swf[128+t] = b3[t];
    }

    f32x4 acc[MF][NF];
    #pragma unroll
    for(int nf=0;nf<NF;nf++){
        float bsv = bias[co0 + nf*16 + lane15];
        #pragma unroll
        for(int mf=0;mf<MF;mf++) acc[mf][nf] = f32x4{bsv,bsv,bsv,bsv};
    }

    auto stage = [&](int buf, int kc){
        constexpr int NIT = (SLOTS + NTH - 1)/NTH;
        #pragma unroll
        for(int it=0; it<NIT; ++it){
            int s = it*NTH + t;
            if(s >= SLOTS) continue;
            int srow = s/272, rem = s - srow*272;
            int spx = rem>>3, ggp = rem&7;
            int gg = ggp ^ (spx&7);
            int gy = row0-1+srow, gx = col0-1+spx;
            bool ok = ((unsigned)gy<256u) && ((unsigned)gx<256u);
            const u16* src = ok ? (inb + (size_t)((gy<<8)+gx)*CSTRIDE + kc + gg*8) : zpad;
            __builtin_amdgcn_global_load_lds(
                (const __attribute__((address_space(1))) u32*)src,
                (__attribute__((address_space(3))) u32*)&sT[buf*SLOTS + s],
                16, 0, 0);
        }
    };

    stage(0, 0);
    __syncthreads();

    int cur = 0;
    for(int j=0;j<NCHUNK;j++){
        if(j+1 < NCHUNK) stage(cur^1, (j+1)*64);
        if(CINTOT==288 && j==NCHUNK-1)
            conv_steps<MF,NF,KBGT,NCO,1>(&sT[cur*SLOTS], wf, j*2, co0, lane15, lgrp, acc);
        else
            conv_steps<MF,NF,KBGT,NCO,2>(&sT[cur*SLOTS], wf, j*2, co0, lane15, lgrp, acc);
        if(j+1 < NCHUNK){
            __syncthreads();
            cur ^= 1;
        }
    }

    if(!FUSE){
        u16* outb = out16 + (size_t)bb*HW*NCO;
        #pragma unroll
        for(int mf=0;mf<MF;mf++){
            int prow  = row0 + (mf>>1);
            int pcolb = col0 + (mf&1)*16 + lgrp*4;
            #pragma unroll
            for(int nf=0;nf<NF;nf++){
                int co = co0 + nf*16 + lane15;
                #pragma unroll
                for(int r=0;r<4;r++){
                    int pix = (prow<<8) + pcolb + r;
                    float v = acc[mf][nf][r];
                    v = (v>0.f) ? v : 0.2f*v;
                    outb[(size_t)pix*NCO + co] = f2b(v);
                }
            }
        }
    } else {
        // h2 tile -> LDS (XOR-swizzled 16B ch-groups within each px's 128B row)
        __syncthreads();                          // conv reads of sT complete
        u16* hl = (u16*)sT;
        #pragma unroll
        for(int mf=0;mf<MF;mf++){
            int lrow = mf>>1;
            int lcol = (mf&1)*16 + lgrp*4;
            #pragma unroll
            for(int nf=0;nf<NF;nf++){
                int ch = co0 + nf*16 + lane15;
                int g  = ch>>3, jj = ch&7;
                #pragma unroll
                for(int r=0;r<4;r++){
                    int px = lrow*32 + lcol + r;
                    float v = acc[mf][nf][r];
                    v = (v>0.f) ? v : 0.2f*v;
                    hl[px*64 + ((g ^ (px&7))<<3) + jj] = f2b(v);
                }
            }
        }
        __syncthreads();
        // one px per thread: flow = tanh(w3 . h2) * 2 * diff; bilinear warp of x31
        int px = t;
        int h = row0 + (px>>5), w = col0 + (px&31);
        int pixg = (bb<<16) + (h<<8) + w;
        const uint4* hv = (const uint4*)hl;
        float f0 = swf[128], f1 = swf[129];
        #pragma unroll
        for(int i=0;i<8;i++){
            uint4 u = hv[px*8 + (i ^ (px&7))];
            float vv[8] = {blo(u.x),bhi(u.x),blo(u.y),bhi(u.y),
                           blo(u.z),bhi(u.z),blo(u.w),bhi(u.w)};
            int cb = i*8;
            #pragma unroll
            for(int j2=0;j2<8;j2++){ f0 += swf[cb+j2]*vv[j2]; f1 += swf[64+cb+j2]*vv[j2]; }
        }
        float d = diff[pixg];
        f0 = tanhf(f0)*2.0f*d;
        f1 = tanhf(f1)*2.0f*d;
        float ix = reflectc((float)w + f0, 256.f);
        float iy = reflectc((float)h + f1, 256.f);
        float x0 = floorf(ix), y0 = floorf(iy);
        float wx = ix-x0, wy = iy-y0;
        int x0i = min(max((int)x0,0),255);
        int x1i = min(x0i+1,255);
        int y0i = min(max((int)y0,0),255);
        int y1i = min(y0i+1,255);
        const u16* p00 = x31 + ((size_t)((bb<<16)+(y0i<<8)+x0i))*32;
        const u16* p01 = x31 + ((size_t)((bb<<16)+(y0i<<8)+x1i))*32;
        const u16* p10 = x31 + ((size_t)((bb<<16)+(y1i<<8)+x0i))*32;
        const u16* p11 = x31 + ((size_t)((bb<<16)+(y1i<<8)+x1i))*32;
        float w00=(1.f-wy)*(1.f-wx), w01=(1.f-wy)*wx, w10=wy*(1.f-wx), w11=wy*wx;
        float* ob = outf + (size_t)bb*CH*HW + (h<<8) + w;
        #pragma unroll
        for(int c=0;c<CH;c++){
            ob[(size_t)c*HW] = w00*b1f(p00[c]) + w01*b1f(p01[c])
                             + w10*b1f(p10[c]) + w11*b1f(p11[c]);
        }
    }
}

extern "C" void kernel_launch(void* const* d_in, const int* in_sizes, int n_in,
                              void* d_out, int out_size, void* d_ws, size_t ws_size,
                              hipStream_t stream) {
    const float* x    = (const float*)d_in[0];
    const float* y    = (const float*)d_in[1];
    const float* srf  = (const float*)d_in[2];
    const float* chw  = (const float*)d_in[3];
    const float* chb  = (const float*)d_in[4];
    const float* qw   = (const float*)d_in[5];
    const float* qb   = (const float*)d_in[6];
    const float* kw   = (const float*)d_in[7];
    const float* kb   = (const float*)d_in[8];
    const float* w1   = (const float*)d_in[9];
    const float* b1p  = (const float*)d_in[10];
    const float* w2   = (const float*)d_in[11];
    const float* b2p  = (const float*)d_in[12];
    const float* w3   = (const float*)d_in[13];
    const float* b3p  = (const float*)d_in[14];

    struct Arena {
        u16 *x31, *regin, *h1, *w1f, *w2f, *zpad;
        float *xp, *stats, *diff;
        float2 *part;
    };
    auto layout = [&](char* base, int G, Arena* A)->size_t{
        size_t o = 0;
        auto take = [&](size_t sz)->char*{ char* p = base ? base+o : 0; o += (sz+255)&~255ull; return p; };
        Arena tmpA; Arena* P = A ? A : &tmpA;
        P->x31   = (u16*)  take((size_t)G*HW*32*2);
        P->xp    = (float*)take((size_t)G*3*HW*4);
        P->stats = (float*)take(6*4*2*4);
        P->part  = (float2*)take((size_t)6*4*64*8);
        P->diff  = (float*)take((size_t)G*HW*4);
        P->regin = (u16*)  take((size_t)G*HW*REGC*2);
        P->h1    = (u16*)  take((size_t)G*HW*128*2);
        P->w1f   = (u16*)  take((size_t)9*9*128*32*2);
        P->w2f   = (u16*)  take((size_t)9*4*64*32*2);
        P->zpad  = (u16*)  take(64);
        return o;
    };

    int G = 4;
    while(G > 1 && layout(nullptr, G, nullptr) > ws_size) G >>= 1;
    Arena A;
    layout((char*)d_ws, G, &A);

    k_wre<<<1296, 256, 0, stream>>>(w1, w2, A.w1f, A.w2f, A.zpad);

    for(int g0=0; g0<4; g0+=G){
        int NB = G;
        const float* xg  = x + (size_t)g0*CIN2*HW;
        const float* yg  = y + (size_t)g0*CM*HW;
        float* outg      = (float*)d_out + (size_t)g0*CH*HW;

        k_conv_half<<<NB*256,  256, 0, stream>>>(xg, chw, chb, srf, A.x31, A.xp);
        k_stats1   <<<NB*384,  256, 0, stream>>>(A.xp, yg, A.part, NB);
        k_stats2   <<<NB*6,     64, 0, stream>>>(A.part, A.stats);
        k_ssim     <<<NB*64,   256, 0, stream>>>(A.xp, yg, A.stats, A.diff, A.regin, NB);
        k_qk       <<<NB*2048, 128, 0, stream>>>(A.x31, yg, qw, qb, kw, kb, A.regin);
        k_corr     <<<NB*512,  256, 0, stream>>>(A.regin, A.regin);
        k_conv3<288,288,128,9,4,0><<<NB*512, 128, 0, stream>>>(
            A.regin, A.w1f, b1p, A.h1, nullptr, nullptr, nullptr, nullptr, nullptr, A.zpad);
        k_conv3<128,128, 64,4,4,1><<<NB*512, 128, 0, stream>>>(
            A.h1, A.w2f, b2p, nullptr, outg, w3, b3p, A.diff, A.x31, A.zpad);
    }
}

// Round 18
// 600.849 us; speedup vs baseline: 1.4266x; 1.0726x over previous
//
#include <hip/hip_runtime.h>
#include <hip/hip_bf16.h>
#include <math.h>

// R18: k_corr micro-opts on the proven R14 structure: (1) XCD-chunked block
// swizzle (halo re-reads become local-L2 hits), (2) q-load + q-norm hoisted
// above staging (HBM latency hides under the staging burst). Everything else
// identical to R17 (644us).

#define HH 256
#define WWI 256
#define HW 65536
#define CH 31
#define CIN2 62
#define CM 3
#define CE 128
#define REGC 288
#define C1S 1e-4f
#define C2S 9e-4f

typedef unsigned short u16;
typedef unsigned int u32;
typedef short bf16x8 __attribute__((ext_vector_type(8)));
typedef float f32x4 __attribute__((ext_vector_type(4)));

__device__ __forceinline__ float blo(u32 u){ return __uint_as_float(u << 16); }
__device__ __forceinline__ float bhi(u32 u){ return __uint_as_float(u & 0xffff0000u); }
__device__ __forceinline__ float b1f(u16 u){ return __uint_as_float(((u32)u) << 16); }
__device__ __forceinline__ u16 f2b(float f){
    u32 u = __float_as_uint(f);
    u32 r = (u + 0x7fffu + ((u >> 16) & 1u)) >> 16;
    return (u16)r;
}
__device__ __forceinline__ f32x4 mfma16(bf16x8 a, bf16x8 b, f32x4 c){
    return __builtin_amdgcn_mfma_f32_16x16x32_bf16(a, b, c, 0, 0, 0);
}
__device__ __forceinline__ float reflectc(float coord, float size){
    float c = fabsf(coord + 0.5f);
    float extra = fmodf(c, size);
    float flips = floorf(c/size);
    float fo = fmodf(flips, 2.0f);
    float r = (fo == 0.0f) ? (extra - 0.5f) : (size - extra - 0.5f);
    return fminf(fmaxf(r, 0.0f), size - 1.0f);
}

// ---------------- 1) conv_half + project fused --------------------------------------
__global__ void k_conv_half(const float* __restrict__ x, const float* __restrict__ w,
                            const float* __restrict__ bias, const float* __restrict__ srf,
                            u16* __restrict__ x31, float* __restrict__ xp){
    __shared__ float sw[CH*CIN2];
    __shared__ float sb[CH+1];
    __shared__ float ssrf[CM*CH];
    for(int i=threadIdx.x;i<CH*CIN2;i+=256) sw[i]=w[i];
    for(int i=threadIdx.x;i<CH;i+=256) sb[i]=bias[i];
    for(int i=threadIdx.x;i<CM*CH;i+=256) ssrf[i]=srf[i];
    __syncthreads();
    int pixg = blockIdx.x*256 + threadIdx.x;
    int b = pixg>>16, hw = pixg&65535;
    float acc[CH];
    #pragma unroll
    for(int c=0;c<CH;c++) acc[c]=sb[c];
    for(int ci=0;ci<CIN2;ci++){
        float xv = x[((size_t)(b*CIN2+ci))*HW + hw];
        #pragma unroll
        for(int c=0;c<CH;c++) acc[c] += sw[c*CIN2+ci]*xv;
    }
    u16* o = x31 + (size_t)pixg*32;
    #pragma unroll
    for(int c=0;c<CH;c++) o[c]=f2b(acc[c]);
    o[31]=0;
    #pragma unroll
    for(int m=0;m<CM;m++){
        float a=0.f;
        #pragma unroll
        for(int c=0;c<CH;c++) a += ssrf[m*CH+c]*acc[c];
        a = fminf(fmaxf(a,-1.f),1.f);
        xp[((size_t)(b*CM+m))*HW + hw] = a;
    }
}

// ---------------- 3a) stats stage 1 ---------------------------------------------------
__global__ void k_stats1(const float* __restrict__ xp, const float* __restrict__ y,
                         float2* __restrict__ part, int NB){
    int bid = blockIdx.x;
    int p = bid >> 6, c = bid & 63;
    const float* src = (p<3*NB) ? (xp + (size_t)p*HW) : (y + (size_t)(p-3*NB)*HW);
    const float4* s4 = (const float4*)(src + c*1024);
    float4 v = s4[threadIdx.x];
    float s  = v.x + v.y + v.z + v.w;
    float ss = v.x*v.x + v.y*v.y + v.z*v.z + v.w*v.w;
    #pragma unroll
    for(int t=1;t<64;t<<=1){ s += __shfl_xor(s,t); ss += __shfl_xor(ss,t); }
    __shared__ float rs[4], rss[4];
    int wid = threadIdx.x>>6, lane = threadIdx.x&63;
    if(lane==0){ rs[wid]=s; rss[wid]=ss; }
    __syncthreads();
    if(threadIdx.x==0){
        part[bid] = float2{rs[0]+rs[1]+rs[2]+rs[3], rss[0]+rss[1]+rss[2]+rss[3]};
    }
}

// ---------------- 3b) stats stage 2 ---------------------------------------------------
__global__ void k_stats2(const float2* __restrict__ part, float* __restrict__ stats){
    int p = blockIdx.x;
    float2 pa = part[p*64 + threadIdx.x];
    float s = pa.x, ss = pa.y;
    #pragma unroll
    for(int t=1;t<64;t<<=1){ s += __shfl_xor(s,t); ss += __shfl_xor(ss,t); }
    if(threadIdx.x==0){
        float mean = s/(float)HW;
        float var = (ss - s*s/(float)HW) / (float)(HW-1);
        stats[p*2]   = mean;
        stats[p*2+1] = sqrtf(fmaxf(var,0.f));
    }
}

// ---------------- 4) fused SSIM (align + 2D gaussian + difficulty) --------------------
__global__ __launch_bounds__(256) void k_ssim(const float* __restrict__ xp,
                                              const float* __restrict__ y,
                                              const float* __restrict__ stats,
                                              float* __restrict__ diff,
                                              u16* __restrict__ regin, int NB){
    __shared__ float sxa[1600];
    __shared__ float sy2[1600];
    __shared__ float hs[5][1280];
    int t = threadIdx.x;
    int bid = blockIdx.x;
    int bb = bid >> 6;
    int s2 = bid & 63;
    int tx = s2 & 7, ty = s2 >> 3;
    float g[9]; float gs = 0.f;
    #pragma unroll
    for(int k=0;k<9;k++){ float cc=(float)(k-4); g[k]=expf(-cc*cc/4.5f); gs+=g[k]; }
    float ginv = 1.f/gs;
    #pragma unroll
    for(int k=0;k<9;k++) g[k] *= ginv;

    float msum[4] = {0.f,0.f,0.f,0.f};
    for(int m=0;m<3;m++){
        int plane = bb*3+m;
        float sm = stats[plane*2],        ssd = stats[plane*2+1];
        float rm = stats[(plane+3*NB)*2], rsd = stats[(plane+3*NB)*2+1];
        const float* xpp = xp + (size_t)plane*HW;
        const float* yp  = y  + (size_t)plane*HW;
        if(m) __syncthreads();
        #pragma unroll
        for(int it=0; it<7; ++it){
            int s = it*256 + t;
            if(s < 1600){
                int rr = s/40, cc = s - rr*40;
                int gy = ty*32-4+rr, gx = tx*32-4+cc;
                float xv=0.f, yv=0.f;
                if(((unsigned)gy<256u)&&((unsigned)gx<256u)){
                    float v = xpp[(gy<<8)+gx];
                    v = (v-sm)/(ssd+1e-6f)*rsd + rm;
                    xv = fminf(fmaxf(v,-1.f),1.f);
                    yv = yp[(gy<<8)+gx];
                }
                sxa[s]=xv; sy2[s]=yv;
            }
        }
        __syncthreads();
        #pragma unroll
        for(int it=0; it<5; ++it){
            int s = it*256 + t;
            int rr = s>>5, cc = s&31;
            int base = rr*40 + cc;
            float s0=0,s1=0,s2v=0,s3=0,s4=0;
            #pragma unroll
            for(int k=0;k<9;k++){
                float gg=g[k];
                float a=sxa[base+k], b=sy2[base+k];
                s0+=gg*a; s1+=gg*b; s2v+=gg*a*a; s3+=gg*b*b; s4+=gg*a*b;
            }
            hs[0][s]=s0; hs[1][s]=s1; hs[2][s]=s2v; hs[3][s]=s3; hs[4][s]=s4;
        }
        __syncthreads();
        #pragma unroll
        for(int it=0; it<4; ++it){
            int s = it*256 + t;
            int rr = s>>5, cc = s&31;
            float v0=0,v1=0,v2=0,v3=0,v4=0;
            #pragma unroll
            for(int k=0;k<9;k++){
                float gg=g[k];
                int idx=(rr+k)*32+cc;
                v0+=gg*hs[0][idx]; v1+=gg*hs[1][idx]; v2+=gg*hs[2][idx];
                v3+=gg*hs[3][idx]; v4+=gg*hs[4][idx];
            }
            float mu1=v0, mu2=v1;
            float mu1s=mu1*mu1, mu2s=mu2*mu2, mu12=mu1*mu2;
            float sg1=v2-mu1s, sg2=v3-mu2s, sg12=v4-mu12;
            msum[it] += (2.f*mu12+C1S)*(2.f*sg12+C2S)
                      / ((mu1s+mu2s+C1S)*(sg1+sg2+C2S));
        }
    }
    #pragma unroll
    for(int it=0; it<4; ++it){
        int s = it*256 + t;
        int rr = s>>5, cc = s&31;
        int pixg = (bb<<16) + ((ty*32+rr)<<8) + (tx*32+cc);
        float d = fminf(fmaxf((1.f-msum[it]*(1.f/3.f))*0.5f,0.f),1.f);
        diff[pixg] = d;
        regin[(size_t)pixg*REGC + 281] = f2b(d);
    }
}

// ---------------- 7) q,k 1x1 convs -> regin bf16 (32 px per block) --------------------
__global__ __launch_bounds__(128) void k_qk(const u16* __restrict__ x31,
                     const float* __restrict__ y,
                     const float* __restrict__ qw, const float* __restrict__ qb,
                     const float* __restrict__ kw, const float* __restrict__ kb,
                     u16* __restrict__ regin){
    __shared__ float sqw[CE*CH];
    __shared__ float skw[CE*CM];
    __shared__ float sqb[CE], skb[CE];
    for(int i=threadIdx.x;i<CE*CH;i+=128) sqw[i]=qw[i];
    for(int i=threadIdx.x;i<CE*CM;i+=128) skw[i]=kw[i];
    if(threadIdx.x<CE){ sqb[threadIdx.x]=qb[threadIdx.x]; skb[threadIdx.x]=kb[threadIdx.x]; }
    __syncthreads();
    int co = threadIdx.x;
    int p0 = blockIdx.x*32;
    float wk0 = skw[co*CM+0], wk1 = skw[co*CM+1], wk2 = skw[co*CM+2];
    for(int pp=0;pp<32;pp++){
        int pixg = p0+pp;
        int b = pixg>>16, hw = pixg&65535;
        const u16* xr = x31 + (size_t)pixg*32;
        float acc = sqb[co];
        #pragma unroll
        for(int c=0;c<CH;c++) acc += sqw[co*CH+c]*b1f(xr[c]);
        u16* rg = regin + (size_t)pixg*REGC;
        rg[co] = f2b(acc);
        float ack = skb[co] + wk0*y[((size_t)(b*CM  ))*HW+hw]
                            + wk1*y[((size_t)(b*CM+1))*HW+hw]
                            + wk2*y[((size_t)(b*CM+2))*HW+hw];
        rg[128+co] = f2b(ack);
        if(co<6) rg[282+co] = 0;
    }
}

// ---------------- 9) correlation volume: LDS-staged K + fused norms -------------------
// R18: XCD-chunked block swizzle + q prefetch hoisted above staging.
__global__ __launch_bounds__(256) void k_corr(const u16* __restrict__ regin,
                                              u16* __restrict__ regout){
    __shared__ uint4 klv[288*16];      // 73,728 B
    __shared__ float kinvl[288];
    int t = threadIdx.x;
    int half = t & 1, pidx = t >> 1;
    int rb = blockIdx.x;
    int bid = (rb & 7)*(gridDim.x >> 3) + (rb >> 3);   // XCD-chunked (grid % 8 == 0)
    int bb = bid >> 9;
    int s2 = bid & 511;
    int tx = s2 & 7, ty = s2 >> 3;
    int lw = pidx & 31, lh = pidx >> 5;
    int w = tx*32 + lw;
    int h = ty*4 + lh;
    int pixg = (bb<<16) + (h<<8) + w;

    // q prefetch + q-norm BEFORE staging (latency hides under the staging burst)
    uint4 q[8];
    const uint4* qp = (const uint4*)(regin + (size_t)pixg*REGC) + half*8;
    #pragma unroll
    for(int i=0;i<8;i++) q[i] = qp[i];
    float sq = 0.f;
    #pragma unroll
    for(int i=0;i<8;i++){
        uint4 v = q[i];
        sq += blo(v.x)*blo(v.x)+bhi(v.x)*bhi(v.x) + blo(v.y)*blo(v.y)+bhi(v.y)*bhi(v.y)
            + blo(v.z)*blo(v.z)+bhi(v.z)*bhi(v.z) + blo(v.w)*blo(v.w)+bhi(v.w)*bhi(v.w);
    }
    sq += __shfl_xor(sq, 1);
    float qn = 1.f/fmaxf(sqrtf(sq),1e-12f);

    // stage K halo region (edge clamp baked in), swizzled uint4 slots
    #pragma unroll
    for(int it=0; it<18; ++it){
        int s = it*256 + t;
        int rpx = s >> 4, g = s & 15;
        int rr = rpx/36, cc = rpx - rr*36;
        int gy = min(max(ty*4-2+rr,0),255);
        int gx = min(max(tx*32-2+cc,0),255);
        const uint4* src = (const uint4*)(regin + ((size_t)((bb<<16)+(gy<<8)+gx))*REGC + 128);
        klv[rpx*16 + (g ^ (rpx&15))] = src[g];
    }
    __syncthreads();

    // kinv from staged K: 576 (px,half) items, pair-shfl combine
    #pragma unroll
    for(int it=0; it<3; ++it){
        int item = it*256 + t;
        int px = item>>1, hf = item&1;
        float s = 0.f;
        if(item < 576){
            const uint4* kp = &klv[px*16];
            int sw = px & 15;
            #pragma unroll
            for(int i=0;i<8;i++){
                uint4 kv = kp[(hf*8+i)^sw];
                s += blo(kv.x)*blo(kv.x)+bhi(kv.x)*bhi(kv.x)
                   + blo(kv.y)*blo(kv.y)+bhi(kv.y)*bhi(kv.y)
                   + blo(kv.z)*blo(kv.z)+bhi(kv.z)*bhi(kv.z)
                   + blo(kv.w)*blo(kv.w)+bhi(kv.w)*bhi(kv.w);
            }
        }
        float so = s + __shfl_xor(s,1);
        if(item < 576 && hf==0) kinvl[px] = 1.f/fmaxf(sqrtf(so),1e-12f);
    }
    __syncthreads();

    float res[13];
    #pragma unroll
    for(int dy=-2;dy<=2;dy++){
        #pragma unroll
        for(int dx=-2;dx<=2;dx++){
            int rpx = (lh+2+dy)*36 + (lw+2+dx);
            const uint4* kp = &klv[rpx*16];
            int sw = rpx & 15;
            float s = 0.f;
            #pragma unroll
            for(int i=0;i<8;i++){
                uint4 kv = kp[(half*8 + i) ^ sw];
                uint4 qv = q[i];
                s += blo(qv.x)*blo(kv.x) + bhi(qv.x)*bhi(kv.x);
                s += blo(qv.y)*blo(kv.y) + bhi(qv.y)*bhi(kv.y);
                s += blo(qv.z)*blo(kv.z) + bhi(qv.z)*bhi(kv.z);
                s += blo(qv.w)*blo(kv.w) + bhi(qv.w)*bhi(kv.w);
            }
            s += __shfl_xor(s, 1);
            float cv = s*qn*kinvl[rpx];
            int o = (dy+2)*5 + (dx+2);
            if(o < 13){ if(half==0) res[o] = cv; }
            else      { if(half==1) res[o-13] = cv; }
        }
    }

    u16* rg = regout + (size_t)pixg*REGC + 256;
    if(half==0){
        u16 p[13];
        #pragma unroll
        for(int i=0;i<13;i++) p[i] = f2b(res[i]);
        uint4 v0; u32* v0p = (u32*)&v0;
        #pragma unroll
        for(int i=0;i<4;i++) v0p[i] = (u32)p[2*i] | ((u32)p[2*i+1]<<16);
        *(uint4*)(rg) = v0;
        *(u32*)(rg+8)  = (u32)p[8]  | ((u32)p[9]<<16);
        *(u32*)(rg+10) = (u32)p[10] | ((u32)p[11]<<16);
        rg[12] = p[12];
    } else {
        u16 p[12];
        #pragma unroll
        for(int i=0;i<12;i++) p[i] = f2b(res[i]);
        rg[13] = p[0];
        *(u32*)(rg+14) = (u32)p[1] | ((u32)p[2]<<16);
        uint4 v1; u32* v1p = (u32*)&v1;
        #pragma unroll
        for(int i=0;i<4;i++) v1p[i] = (u32)p[3+2*i] | ((u32)p[4+2*i]<<16);
        *(uint4*)(rg+16) = v1;
        rg[24] = p[11];
    }
}

// ---------------- 10) weight rearrange + zpad clear -----------------------------------
__global__ void k_wre(const float* __restrict__ w1, const float* __restrict__ w2,
                      u16* __restrict__ w1f, u16* __restrict__ w2f,
                      u16* __restrict__ zpad){
    int i = blockIdx.x*256 + threadIdx.x;
    if(i < 32) zpad[i] = 0;
    if(i < 9*9*128*32){
        int j = i & 7;
        int gg = (i>>3)&3;
        int co = (i>>5)&127;
        int rest = i>>12;
        int kbg = rest%9, tap = rest/9;
        int ci = kbg*32 + gg*8 + j;
        float v = (ci<282) ? w1[((size_t)co*282 + ci)*9 + tap] : 0.f;
        w1f[i] = f2b(v);
    }
    if(i < 9*4*64*32){
        int j = i & 7;
        int gg = (i>>3)&3;
        int co = (i>>5)&63;
        int rest = i>>11;
        int kbg = rest&3, tap = rest>>2;
        int ci = kbg*32 + gg*8 + j;
        w2f[i] = f2b(w2[((size_t)co*128 + ci)*9 + tap]);
    }
}

// ---------------- 11+12) MFMA 3x3 conv; r2 variant fuses flow+warp epilogue -----------
template<int MF>
__device__ __forceinline__ void ldaM(const uint4* sbuf, int ky, int kx, int kb,
                                     int lane15, int lgrp, bf16x8* ar){
    #pragma unroll
    for(int mf=0;mf<MF;mf++){
        int spx  = (mf&1)*16 + lane15 + kx;
        int srow = (mf>>1) + ky;
        int slot = (srow*34 + spx)*8 + ((kb*4 + lgrp) ^ (spx&7));
        ar[mf] = *(const bf16x8*)&sbuf[slot];
    }
}

template<int NF, int KBGT, int NCO>
__device__ __forceinline__ void ldbN(const u16* __restrict__ wf, int kbg, int tap,
                                     int co0, int lane15, int lgrp, bf16x8* br){
    #pragma unroll
    for(int nf=0;nf<NF;nf++){
        size_t idx = ((size_t)((tap*KBGT + kbg)*NCO + co0 + nf*16 + lane15))*4 + lgrp;
        br[nf] = *(const bf16x8*)(wf + idx*8);
    }
}

template<int MF, int NF, int KBGT, int NCO, int KBI>
__device__ __forceinline__ void conv_steps(const uint4* sbuf, const u16* __restrict__ wf,
                                           int kbgbase, int co0, int lane15, int lgrp,
                                           f32x4 (&acc)[MF][NF]){
    constexpr int NST = 9*KBI;
    #pragma unroll
    for(int s=0;s<NST;s++){
        int ky,kx,kb;
        if(KBI==2){ ky = s/6; kx = (s>>1)%3; kb = s&1; }
        else      { ky = s/3; kx = s%3;      kb = 0;   }
        bf16x8 a[MF];
        bf16x8 b[NF];
        ldaM<MF>(sbuf, ky,kx,kb, lane15, lgrp, a);
        ldbN<NF,KBGT,NCO>(wf, kbgbase+kb, ky*3+kx, co0, lane15, lgrp, b);
        #pragma unroll
        for(int mf=0;mf<MF;mf++)
            #pragma unroll
            for(int nf=0;nf<NF;nf++)
                acc[mf][nf] = mfma16(a[mf], b[nf], acc[mf][nf]);
    }
}

template<int CSTRIDE, int CINTOT, int NCO, int KBGT, int TM, int FUSE>
__global__ __launch_bounds__(128, 1) void k_conv3(const u16* __restrict__ in,
                                                  const u16* __restrict__ wf,
                                                  const float* __restrict__ bias,
                                                  u16* __restrict__ out16,
                                                  float* __restrict__ outf,
                                                  const float* __restrict__ w3,
                                                  const float* __restrict__ b3,
                                                  const float* __restrict__ diff,
                                                  const u16* __restrict__ x31,
                                                  const u16* __restrict__ zpad){
    constexpr int NW = 2;
    constexpr int NF = NCO/(16*NW);
    constexpr int MF = 2*TM;
    constexpr int NCHUNK = (CINTOT + 63)/64;
    constexpr int NTH = NW*64;
    constexpr int SLOTS = (TM+2)*34*8;
    __shared__ uint4 sT[2*SLOTS];
    __shared__ float swf[132];
    int t = threadIdx.x;
    int lane15 = t & 15, lgrp = (t >> 4) & 3;
    int co0 = (t >> 6) * (NCO/NW);
    int rb = blockIdx.x;
    int bid = (rb & 7)*(gridDim.x >> 3) + (rb >> 3);
    int bb = bid >> 9;
    int s2 = bid & 511;
    int tx = s2 & 7, ty = s2 >> 3;
    int row0 = ty*TM, col0 = tx*32;
    const u16* inb  = in + (size_t)bb*HW*CSTRIDE;

    if(FUSE){
        if(t < 128) swf[t] = w3[t];
        if(t < 2)   swf[128+t] = b3[t];
    }

    f32x4 acc[MF][NF];
    #pragma unroll
    for(int nf=0;nf<NF;nf++){
        float bsv = bias[co0 + nf*16 + lane15];
        #pragma unroll
        for(int mf=0;mf<MF;mf++) acc[mf][nf] = f32x4{bsv,bsv,bsv,bsv};
    }

    auto stage = [&](int buf, int kc){
        constexpr int NIT = (SLOTS + NTH - 1)/NTH;
        #pragma unroll
        for(int it=0; it<NIT; ++it){
            int s = it*NTH + t;
            if(s >= SLOTS) continue;
            int srow = s/272, rem = s - srow*272;
            int spx = rem>>3, ggp = rem&7;
            int gg = ggp ^ (spx&7);
            int gy = row0-1+srow, gx = col0-1+spx;
            bool ok = ((unsigned)gy<256u) && ((unsigned)gx<256u);
            const u16* src = ok ? (inb + (size_t)((gy<<8)+gx)*CSTRIDE + kc + gg*8) : zpad;
            __builtin_amdgcn_global_load_lds(
                (const __attribute__((address_space(1))) u32*)src,
                (__attribute__((address_space(3))) u32*)&sT[buf*SLOTS + s],
                16, 0, 0);
        }
    };

    stage(0, 0);
    __syncthreads();

    int cur = 0;
    for(int j=0;j<NCHUNK;j++){
        if(j+1 < NCHUNK) stage(cur^1, (j+1)*64);
        if(CINTOT==288 && j==NCHUNK-1)
            conv_steps<MF,NF,KBGT,NCO,1>(&sT[cur*SLOTS], wf, j*2, co0, lane15, lgrp, acc);
        else
            conv_steps<MF,NF,KBGT,NCO,2>(&sT[cur*SLOTS], wf, j*2, co0, lane15, lgrp, acc);
        if(j+1 < NCHUNK){
            __syncthreads();
            cur ^= 1;
        }
    }

    if(!FUSE){
        u16* outb = out16 + (size_t)bb*HW*NCO;
        #pragma unroll
        for(int mf=0;mf<MF;mf++){
            int prow  = row0 + (mf>>1);
            int pcolb = col0 + (mf&1)*16 + lgrp*4;
            #pragma unroll
            for(int nf=0;nf<NF;nf++){
                int co = co0 + nf*16 + lane15;
                #pragma unroll
                for(int r=0;r<4;r++){
                    int pix = (prow<<8) + pcolb + r;
                    float v = acc[mf][nf][r];
                    v = (v>0.f) ? v : 0.2f*v;
                    outb[(size_t)pix*NCO + co] = f2b(v);
                }
            }
        }
    } else {
        __syncthreads();
        u16* hl = (u16*)sT;
        #pragma unroll
        for(int mf=0;mf<MF;mf++){
            int lrow = mf>>1;
            int lcol = (mf&1)*16 + lgrp*4;
            #pragma unroll
            for(int nf=0;nf<NF;nf++){
                int ch = co0 + nf*16 + lane15;
                int g  = ch>>3, jj = ch&7;
                #pragma unroll
                for(int r=0;r<4;r++){
                    int px = lrow*32 + lcol + r;
                    float v = acc[mf][nf][r];
                    v = (v>0.f) ? v : 0.2f*v;
                    hl[px*64 + ((g ^ (px&7))<<3) + jj] = f2b(v);
                }
            }
        }
        __syncthreads();
        int px = t;
        int h = row0 + (px>>5), w = col0 + (px&31);
        int pixg = (bb<<16) + (h<<8) + w;
        const uint4* hv = (const uint4*)hl;
        float f0 = swf[128], f1 = swf[129];
        #pragma unroll
        for(int i=0;i<8;i++){
            uint4 u = hv[px*8 + (i ^ (px&7))];
            float vv[8] = {blo(u.x),bhi(u.x),blo(u.y),bhi(u.y),
                           blo(u.z),bhi(u.z),blo(u.w),bhi(u.w)};
            int cb = i*8;
            #pragma unroll
            for(int j2=0;j2<8;j2++){ f0 += swf[cb+j2]*vv[j2]; f1 += swf[64+cb+j2]*vv[j2]; }
        }
        float d = diff[pixg];
        f0 = tanhf(f0)*2.0f*d;
        f1 = tanhf(f1)*2.0f*d;
        float ix = reflectc((float)w + f0, 256.f);
        float iy = reflectc((float)h + f1, 256.f);
        float x0 = floorf(ix), y0 = floorf(iy);
        float wx = ix-x0, wy = iy-y0;
        int x0i = min(max((int)x0,0),255);
        int x1i = min(x0i+1,255);
        int y0i = min(max((int)y0,0),255);
        int y1i = min(y0i+1,255);
        const u16* p00 = x31 + ((size_t)((bb<<16)+(y0i<<8)+x0i))*32;
        const u16* p01 = x31 + ((size_t)((bb<<16)+(y0i<<8)+x1i))*32;
        const u16* p10 = x31 + ((size_t)((bb<<16)+(y1i<<8)+x0i))*32;
        const u16* p11 = x31 + ((size_t)((bb<<16)+(y1i<<8)+x1i))*32;
        float w00=(1.f-wy)*(1.f-wx), w01=(1.f-wy)*wx, w10=wy*(1.f-wx), w11=wy*wx;
        float* ob = outf + (size_t)bb*CH*HW + (h<<8) + w;
        #pragma unroll
        for(int c=0;c<CH;c++){
            ob[(size_t)c*HW] = w00*b1f(p00[c]) + w01*b1f(p01[c])
                             + w10*b1f(p10[c]) + w11*b1f(p11[c]);
        }
    }
}

extern "C" void kernel_launch(void* const* d_in, const int* in_sizes, int n_in,
                              void* d_out, int out_size, void* d_ws, size_t ws_size,
                              hipStream_t stream) {
    const float* x    = (const float*)d_in[0];
    const float* y    = (const float*)d_in[1];
    const float* srf  = (const float*)d_in[2];
    const float* chw  = (const float*)d_in[3];
    const float* chb  = (const float*)d_in[4];
    const float* qw   = (const float*)d_in[5];
    const float* qb   = (const float*)d_in[6];
    const float* kw   = (const float*)d_in[7];
    const float* kb   = (const float*)d_in[8];
    const float* w1   = (const float*)d_in[9];
    const float* b1p  = (const float*)d_in[10];
    const float* w2   = (const float*)d_in[11];
    const float* b2p  = (const float*)d_in[12];
    const float* w3   = (const float*)d_in[13];
    const float* b3p  = (const float*)d_in[14];

    struct Arena {
        u16 *x31, *regin, *h1, *w1f, *w2f, *zpad;
        float *xp, *stats, *diff;
        float2 *part;
    };
    auto layout = [&](char* base, int G, Arena* A)->size_t{
        size_t o = 0;
        auto take = [&](size_t sz)->char*{ char* p = base ? base+o : 0; o += (sz+255)&~255ull; return p; };
        Arena tmpA; Arena* P = A ? A : &tmpA;
        P->x31   = (u16*)  take((size_t)G*HW*32*2);
        P->xp    = (float*)take((size_t)G*3*HW*4);
        P->stats = (float*)take(6*4*2*4);
        P->part  = (float2*)take((size_t)6*4*64*8);
        P->diff  = (float*)take((size_t)G*HW*4);
        P->regin = (u16*)  take((size_t)G*HW*REGC*2);
        P->h1    = (u16*)  take((size_t)G*HW*128*2);
        P->w1f   = (u16*)  take((size_t)9*9*128*32*2);
        P->w2f   = (u16*)  take((size_t)9*4*64*32*2);
        P->zpad  = (u16*)  take(64);
        return o;
    };

    int G = 4;
    while(G > 1 && layout(nullptr, G, nullptr) > ws_size) G >>= 1;
    Arena A;
    layout((char*)d_ws, G, &A);

    k_wre<<<1296, 256, 0, stream>>>(w1, w2, A.w1f, A.w2f, A.zpad);

    for(int g0=0; g0<4; g0+=G){
        int NB = G;
        const float* xg  = x + (size_t)g0*CIN2*HW;
        const float* yg  = y + (size_t)g0*CM*HW;
        float* outg      = (float*)d_out + (size_t)g0*CH*HW;

        k_conv_half<<<NB*256,  256, 0, stream>>>(xg, chw, chb, srf, A.x31, A.xp);
        k_stats1   <<<NB*384,  256, 0, stream>>>(A.xp, yg, A.part, NB);
        k_stats2   <<<NB*6,     64, 0, stream>>>(A.part, A.stats);
        k_ssim     <<<NB*64,   256, 0, stream>>>(A.xp, yg, A.stats, A.diff, A.regin, NB);
        k_qk       <<<NB*2048, 128, 0, stream>>>(A.x31, yg, qw, qb, kw, kb, A.regin);
        k_corr     <<<NB*512,  256, 0, stream>>>(A.regin, A.regin);
        k_conv3<288,288,128,9,4,0><<<NB*512, 128, 0, stream>>>(
            A.regin, A.w1f, b1p, A.h1, nullptr, nullptr, nullptr, nullptr, nullptr, A.zpad);
        k_conv3<128,128, 64,4,4,1><<<NB*512, 128, 0, stream>>>(
            A.h1, A.w2f, b2p, nullptr, outg, w3, b3p, A.diff, A.x31, A.zpad);
    }
}